// Round 8
// baseline (1331.976 us; speedup 1.0000x reference)
//
#include <hip/hip_runtime.h>

#define TT 512
#define BB 256
#define CC 65
#define HALFC 32
#define HID 128
#define ODIM 10

// tanh(x) = 2/(1+e^{-2x}) - 1
__device__ __forceinline__ float ftanh(float x) {
  float u = __builtin_amdgcn_exp2f(x * -2.885390082f);
  return fmaf(2.f, __builtin_amdgcn_rcpf(1.f + u), -1.f);
}
// sigmoid(x) = 1/(1+e^{-x})
__device__ __forceinline__ float fsig(float x) {
  float u = __builtin_amdgcn_exp2f(x * -1.442695041f);
  return __builtin_amdgcn_rcpf(1.f + u);
}

template <int CTRL>
__device__ __forceinline__ float dpp_add(float x) {
  return x + __int_as_float(__builtin_amdgcn_update_dpp(
      0, __float_as_int(x), CTRL, 0xF, 0xF, true));
}
// 16-lane row sum via row_shl (toward LOWER lanes, bound_ctrl zeros): after
// shl 1,2,4,8 lane i holds sum src[i..i+15] -> full row sum valid at kk==0.
__device__ __forceinline__ float red16(float x) {
  x = dpp_add<0x101>(x);  // row_shl:1
  x = dpp_add<0x102>(x);  // row_shl:2
  x = dpp_add<0x104>(x);  // row_shl:4
  x = dpp_add<0x108>(x);  // row_shl:8
  return x;
}

// Raw barrier: drain LDS ops, no vmcnt drain (global loads stay in flight).
__device__ __forceinline__ void block_sync_lds() {
  asm volatile("s_waitcnt lgkmcnt(0)" ::: "memory");
  __builtin_amdgcn_s_barrier();
  asm volatile("" ::: "memory");
}
__device__ __forceinline__ void vm_wait0() {
  asm volatile("s_waitcnt vmcnt(0)" ::: "memory");
}

// Permuted 128-float LDS layout (identical to verified R5): logical float4 f
// stored at perm(f) = ((f&3)<<3)|(f>>2). Reads at perm(2kk), perm(2kk+1) for
// kk=0..15 touch each bank exactly twice (2-way alias = free).
__device__ __forceinline__ int permf4(int f) { return ((f & 3) << 3) | (f >> 2); }
__device__ __forceinline__ int slot_byteoff(int s) {
  return permf4(s >> 1) * 16 + (s & 1) * 8;
}

// Per-t scalars: idx (int bits), fr, td, tsub
__global__ void prep0(const float* __restrict__ times, float4* __restrict__ si,
                      int* __restrict__ anyobs) {
  __shared__ float ts[TT];
  int t = threadIdx.x;
  ts[t] = times[t];
  __syncthreads();
  float tv = ts[t];
  int cnt = 0;
  for (int jj = 0; jj < TT; ++jj) cnt += (tv > ts[jj]) ? 1 : 0;
  int idx = cnt - 1;
  idx = min(max(idx, 0), TT - 2);
  float4 o;
  o.x = __int_as_float(idx);
  o.y = tv - ts[idx];
  o.z = (t == 0) ? 0.f : (tv - ts[t - 1]);
  o.w = (t == 0) ? ts[0] : ts[t - 1];
  si[t] = o;
  anyobs[t] = 0;
}

// obs[b,t] = max over diffed channels 1..32 > 0.5 ; anyobs[t] = OR over b
__global__ void prep_obs(const float* __restrict__ ca, const float* __restrict__ cb,
                         const float* __restrict__ cc2, const float* __restrict__ cd,
                         const float4* __restrict__ si, int* __restrict__ anyobs,
                         unsigned char* __restrict__ obs) {
  int grp = blockIdx.x * (blockDim.x >> 5) + (threadIdx.x >> 5);
  int lane = threadIdx.x & 31;
  int t = grp & (TT - 1);
  int b = grp / TT;
  int ch = 1 + lane;
  float4 s = si[t];
  int idx = __float_as_int(s.x);
  float fr = s.y;
  size_t base = ((size_t)b * (TT - 1) + idx) * CC + ch;
  float f3 = fr / 3.f;
  float v = ca[base] + (cb[base] + (0.5f * cc2[base] + cd[base] * f3) * fr) * fr;
  float D = v;
  if (t >= 1) {
    float4 sp = si[t - 1];
    int idxp = __float_as_int(sp.x);
    float frp = sp.y;
    size_t basep = ((size_t)b * (TT - 1) + idxp) * CC + ch;
    float f3p = frp / 3.f;
    float vp = ca[basep] + (cb[basep] + (0.5f * cc2[basep] + cd[basep] * f3p) * frp) * frp;
    D = v - vp;
  }
  float m = D;
  #pragma unroll
  for (int off = 16; off >= 1; off >>= 1) m = fmaxf(m, __shfl_xor(m, off));
  if (lane == 0) {
    unsigned char o = (m > 0.5f) ? (unsigned char)1 : (unsigned char)0;
    obs[(size_t)b * TT + t] = o;
    if (o) atomicOr(&anyobs[t], 1);
  }
}

// One block per batch element. 1024 threads = 16 waves (4/SIMD for latency
// hiding). Thread (wv, jslot=lane>>4, kk=lane&15) owns output pair
// j0 = 2*(wv*4+jslot) over k-rows 8kk..8kk+7. Reduction: red16 DPP row sum.
__launch_bounds__(1024, 4)
__global__ void ode_main(
    const float* __restrict__ ca, const float* __restrict__ cb,
    const float* __restrict__ cc2, const float* __restrict__ cd,
    const int* __restrict__ final_index,
    const float* __restrict__ Wr, const float* __restrict__ br,
    const float* __restrict__ Wz, const float* __restrict__ bz,
    const float* __restrict__ Wxn, const float* __restrict__ bxn,
    const float* __restrict__ Whn, const float* __restrict__ bhn,
    const float* __restrict__ Wode, const float* __restrict__ bode,
    const float* __restrict__ Wlin, const float* __restrict__ blin,
    const float4* __restrict__ si, const int* __restrict__ anyobs,
    const unsigned char* __restrict__ obsArr,
    float* __restrict__ out)
{
  __shared__ alignas(16) float hS[HID];
  __shared__ alignas(16) float vA[HID];
  __shared__ alignas(16) float vB[HID];
  __shared__ alignas(16) float xs[HALFC];
  __shared__ alignas(16) float4 siL[TT];
  __shared__ unsigned char flagL[TT];

  const int tid = threadIdx.x;
  const int b = blockIdx.x;
  const int lane = tid & 63;
  const int wv = tid >> 6;       // 0..15
  const int jslot = lane >> 4;   // 0..3
  const int kk = lane & 15;      // 0..15
  const int spair = wv * 4 + jslot;   // 0..63
  const int j0 = 2 * spair;
  const int wroff = slot_byteoff(spair);

  // ---- weights in registers: w[i] = W[(8*kk+i)*HID + {j0,j0+1}] ----
  float2 wode[8], whn[8], wrh[8], wzh[8];
  float2 wrx[2], wzx[2], wxn[2];
  #pragma unroll
  for (int i = 0; i < 8; ++i) {
    const int row = 8 * kk + i;
    wode[i] = *(const float2*)&Wode[row * HID + j0];
    whn [i] = *(const float2*)&Whn [row * HID + j0];
    wrh [i] = *(const float2*)&Wr[(HALFC + row) * HID + j0];
    wzh [i] = *(const float2*)&Wz[(HALFC + row) * HID + j0];
  }
  #pragma unroll
  for (int i = 0; i < 2; ++i) {
    const int xrow = 2 * kk + i;
    wrx[i] = *(const float2*)&Wr [xrow * HID + j0];
    wzx[i] = *(const float2*)&Wz [xrow * HID + j0];
    wxn[i] = *(const float2*)&Wxn[xrow * HID + j0];
  }
  float bo0, bo1, bh0, bh1, br0, br1, bz0, bz1, bx0, bx1;
  { float2 q;
    q = *(const float2*)&bode[j0]; bo0 = q.x; bo1 = q.y;
    q = *(const float2*)&bhn [j0]; bh0 = q.x; bh1 = q.y;
    q = *(const float2*)&br  [j0]; br0 = q.x; br1 = q.y;
    q = *(const float2*)&bz  [j0]; bz0 = q.x; bz1 = q.y;
    q = *(const float2*)&bxn [j0]; bx0 = q.x; bx1 = q.y;
  }
  const int fidx = final_index[b];

  // ---- stage per-step metadata into LDS (one-time) ----
  if (tid < TT) {
    siL[tid] = si[tid];
    const int ao = anyobs[tid];
    const unsigned char o = obsArr[(size_t)b * TT + tid];
    flagL[tid] = (unsigned char)((ao ? 1 : 0) | (o ? 2 : 0));
  }
  if (tid < HID) { hS[tid] = 0.f; vA[tid] = 0.f; vB[tid] = 0.f; }
  if (tid < HALFC) xs[tid] = 0.f;
  float hj0 = 0.f, hj1 = 0.f;  // valid on kk==0 lanes
  float dtv = 0.f;             // valid on tid==0
  block_sync_lds();

  // matvec over permuted LDS buffer: 8 k-rows x 2 outputs per lane.
  auto mv = [&](const float* __restrict__ buf, const float2 (&w)[8],
                float& o0, float& o1) {
    const float4* b4 = (const float4*)buf;
    const float4 A = b4[permf4(2 * kk)];
    const float4 B4 = b4[permf4(2 * kk + 1)];
    const float vv[8] = {A.x, A.y, A.z, A.w, B4.x, B4.y, B4.z, B4.w};
    float a0 = 0.f, a1 = 0.f;
    #pragma unroll
    for (int i = 0; i < 8; ++i) {
      a0 = fmaf(vv[i], w[i].x, a0);
      a1 = fmaf(vv[i], w[i].y, a1);
    }
    o0 = red16(a0);
    o1 = red16(a1);
  };

  float4 s = siL[0];
  int flg = flagL[0];

  for (int t = 0; ; ++t) {
    const int sidx = __float_as_int(s.x);
    const float fr = s.y, td = s.z, tsub = s.w;
    const bool apply = (flg & 1) && (flg & 2);

    // Issue x-coeff global loads early; stay in flight across raw barriers.
    float xa = 0.f, xb = 0.f, xc = 0.f, xd = 0.f;
    float ya = 0.f, yb = 0.f, yc = 0.f, yd = 0.f;
    if (tid < 32) {
      const size_t base = ((size_t)b * (TT - 1) + sidx) * CC;
      const int ch = 33 + tid;
      xa = ca[base + ch]; xb = cb[base + ch]; xc = cc2[base + ch]; xd = cd[base + ch];
      if (tid == 0) { ya = ca[base]; yb = cb[base]; yc = cc2[base]; yd = cd[base]; }
    }

    if (t > 0) {
      const float htd = 0.5f * td;
      float p0, p1, k0, k1, ks0, ks1;
      // stage 1: k1 = f(h)
      mv(hS, wode, p0, p1);
      k0 = ftanh(p0 + bo0); k1 = ftanh(p1 + bo1);
      ks0 = k0; ks1 = k1;
      if (kk == 0)
        *(float2*)((char*)vA + wroff) =
            make_float2(fmaf(htd, k0, hj0), fmaf(htd, k1, hj1));
      block_sync_lds();
      // stage 2: k2 = f(h + td/2 k1)
      mv(vA, wode, p0, p1);
      k0 = ftanh(p0 + bo0); k1 = ftanh(p1 + bo1);
      ks0 = fmaf(2.f, k0, ks0); ks1 = fmaf(2.f, k1, ks1);
      if (kk == 0)
        *(float2*)((char*)vB + wroff) =
            make_float2(fmaf(htd, k0, hj0), fmaf(htd, k1, hj1));
      block_sync_lds();
      // stage 3: k3 = f(h + td/2 k2)
      mv(vB, wode, p0, p1);
      k0 = ftanh(p0 + bo0); k1 = ftanh(p1 + bo1);
      ks0 = fmaf(2.f, k0, ks0); ks1 = fmaf(2.f, k1, ks1);
      if (kk == 0)
        *(float2*)((char*)vA + wroff) =
            make_float2(fmaf(td, k0, hj0), fmaf(td, k1, hj1));
      block_sync_lds();
      // stage 4: k4 = f(h + td k3); h += td/6 (k1+2k2+2k3+k4)
      mv(vA, wode, p0, p1);
      k0 = ftanh(p0 + bo0); k1 = ftanh(p1 + bo1);
      ks0 += k0; ks1 += k1;
      hj0 = fmaf(td * (1.f / 6.f), ks0, hj0);
      hj1 = fmaf(td * (1.f / 6.f), ks1, hj1);
      if (kk == 0)
        *(float2*)((char*)vB + wroff) = make_float2(hj0, hj1);
    }

    // Spline -> xs (tid<32). Wait for the global loads (hidden under RK4).
    float xdelta = 0.f;
    vm_wait0();
    if (tid < 32) {
      const float f3 = fr * (1.f / 3.f);
      float sv = xa + (xb + (0.5f * xc + xd * f3) * fr) * fr;
      if (tid == 0) {
        const float s0 = ya + (yb + (0.5f * yc + yd * f3) * fr) * fr;
        xdelta = s0 - tsub;
        sv += dtv;  // Xp[:,0] += dt
      }
      xs[tid] = sv;
    }
    block_sync_lds();  // covers vB (evolved h) and xs

    // GRU
    {
      const float4* b4 = (const float4*)vB;
      const float4 A = b4[permf4(2 * kk)];
      const float4 B4 = b4[permf4(2 * kk + 1)];
      const float vv[8] = {A.x, A.y, A.z, A.w, B4.x, B4.y, B4.z, B4.w};
      float rp0 = 0.f, rp1 = 0.f, zp0 = 0.f, zp1 = 0.f;
      float gp0 = 0.f, gp1 = 0.f, xp0 = 0.f, xp1 = 0.f;
      #pragma unroll
      for (int i = 0; i < 8; ++i) {
        rp0 = fmaf(vv[i], wrh[i].x, rp0); rp1 = fmaf(vv[i], wrh[i].y, rp1);
        zp0 = fmaf(vv[i], wzh[i].x, zp0); zp1 = fmaf(vv[i], wzh[i].y, zp1);
        gp0 = fmaf(vv[i], whn[i].x, gp0); gp1 = fmaf(vv[i], whn[i].y, gp1);
      }
      const float2 xv = ((const float2*)xs)[kk];
      rp0 = fmaf(xv.x, wrx[0].x, fmaf(xv.y, wrx[1].x, rp0));
      rp1 = fmaf(xv.x, wrx[0].y, fmaf(xv.y, wrx[1].y, rp1));
      zp0 = fmaf(xv.x, wzx[0].x, fmaf(xv.y, wzx[1].x, zp0));
      zp1 = fmaf(xv.x, wzx[0].y, fmaf(xv.y, wzx[1].y, zp1));
      xp0 = fmaf(xv.x, wxn[0].x, fmaf(xv.y, wxn[1].x, xp0));
      xp1 = fmaf(xv.x, wxn[0].y, fmaf(xv.y, wxn[1].y, xp1));
      rp0 = red16(rp0); rp1 = red16(rp1);
      zp0 = red16(zp0); zp1 = red16(zp1);
      gp0 = red16(gp0); gp1 = red16(gp1);
      xp0 = red16(xp0); xp1 = red16(xp1);
      // acts computed on all lanes; only kk==0's values are valid/stored
      const float r0 = fsig(rp0 + br0), r1 = fsig(rp1 + br1);
      const float z0 = fsig(zp0 + bz0), z1 = fsig(zp1 + bz1);
      const float n0 = ftanh(xp0 + bx0 + (gp0 + bh0) * r0);
      const float n1 = ftanh(xp1 + bx1 + (gp1 + bh1) * r1);
      const float h0n = fmaf(z0, hj0 - n0, n0);
      const float h1n = fmaf(z1, hj1 - n1, n1);
      hj0 = apply ? h0n : hj0;
      hj1 = apply ? h1n : hj1;
      if (kk == 0)
        *(float2*)((char*)hS + wroff) = make_float2(hj0, hj1);
    }
    if (tid == 0 && (flg & 1) && !(flg & 2)) dtv += xdelta;

    if (t == fidx) break;
    // prefetch next step's metadata from LDS
    const int tn = t + 1;
    s = siL[tn];
    flg = flagL[tn];
    block_sync_lds();  // hS visible for next stage 1
  }

  block_sync_lds();
  // final projection: out = h @ W_lin + b_lin (de-permute hS reads)
  if (tid < ODIM) {
    float acc = blin[tid];
    const float* hf = (const float*)hS;
    #pragma unroll 8
    for (int q = 0; q < HID; ++q) {
      const float hv = hf[permf4(q >> 2) * 4 + (q & 3)];
      acc = fmaf(hv, Wlin[q * ODIM + tid], acc);
    }
    out[b * ODIM + tid] = acc;
  }
}

extern "C" void kernel_launch(void* const* d_in, const int* in_sizes, int n_in,
                              void* d_out, int out_size, void* d_ws, size_t ws_size,
                              hipStream_t stream) {
  const float* times = (const float*)d_in[0];
  const float* ca   = (const float*)d_in[1];
  const float* cb   = (const float*)d_in[2];
  const float* cc2  = (const float*)d_in[3];
  const float* cd   = (const float*)d_in[4];
  const int*   fidx = (const int*)d_in[5];
  const float* Wr   = (const float*)d_in[6];
  const float* br   = (const float*)d_in[7];
  const float* Wz   = (const float*)d_in[8];
  const float* bz   = (const float*)d_in[9];
  const float* Wxn  = (const float*)d_in[10];
  const float* bxn  = (const float*)d_in[11];
  const float* Whn  = (const float*)d_in[12];
  const float* bhn  = (const float*)d_in[13];
  const float* Wode = (const float*)d_in[14];
  const float* bode = (const float*)d_in[15];
  const float* Wlin = (const float*)d_in[16];
  const float* blin = (const float*)d_in[17];
  float* out = (float*)d_out;

  char* ws = (char*)d_ws;
  float4* si = (float4*)ws;                                     // TT*16 B
  int* anyobs = (int*)(ws + TT * 16);                           // TT*4 B
  unsigned char* obs = (unsigned char*)(ws + TT * 16 + TT * 4); // BB*TT B

  prep0<<<1, TT, 0, stream>>>(times, si, anyobs);
  prep_obs<<<(BB * TT) / 8, 256, 0, stream>>>(ca, cb, cc2, cd, si, anyobs, obs);
  ode_main<<<BB, 1024, 0, stream>>>(ca, cb, cc2, cd, fidx, Wr, br, Wz, bz,
                                    Wxn, bxn, Whn, bhn, Wode, bode, Wlin, blin,
                                    si, anyobs, obs, out);
}

// Round 9
// 1123.446 us; speedup vs baseline: 1.1856x; 1.1856x over previous
//
#include <hip/hip_runtime.h>

#define TT 512
#define BB 256
#define CC 65
#define HALFC 32
#define HID 128
#define ODIM 10

// tanh(x) = 2/(1+e^{-2x}) - 1 : mul, exp2, add, rcp, fma (2 transcendentals)
__device__ __forceinline__ float ftanh(float x) {
  float u = __builtin_amdgcn_exp2f(x * -2.885390082f);  // e^{-2x}
  return fmaf(2.f, __builtin_amdgcn_rcpf(1.f + u), -1.f);
}
// sigmoid(x) = 1/(1+e^{-x})
__device__ __forceinline__ float fsig(float x) {
  float u = __builtin_amdgcn_exp2f(x * -1.442695041f);
  return __builtin_amdgcn_rcpf(1.f + u);
}

template <int CTRL>
__device__ __forceinline__ float dpp_add(float x) {
  return x + __int_as_float(__builtin_amdgcn_update_dpp(
      0, __float_as_int(x), CTRL, 0xF, 0xF, true));
}
// 8-lane subgroup sum via row_shl (data moves toward LOWER lanes; bound_ctrl
// zeros beyond the row edge): dest[i] = sum src[i..i+7]. Valid at (lane&7)==0.
__device__ __forceinline__ float red8(float x) {
  x = dpp_add<0x101>(x);  // row_shl:1
  x = dpp_add<0x102>(x);  // row_shl:2
  x = dpp_add<0x104>(x);  // row_shl:4
  return x;
}

// Raw barrier: drain LDS ops, no vmcnt drain (global loads stay in flight).
__device__ __forceinline__ void block_sync_lds() {
  asm volatile("s_waitcnt lgkmcnt(0)" ::: "memory");
  __builtin_amdgcn_s_barrier();
  asm volatile("" ::: "memory");
}
__device__ __forceinline__ void vm_wait0() {
  asm volatile("s_waitcnt vmcnt(0)" ::: "memory");
}

// Permuted 128-float LDS layout: logical float4 f (=v[4f..4f+3]) stored at
// float4 index perm(f) = ((f&3)<<3) | (f>>2). Thread kk's k-slice
// {v[16kk+4q+e]} is logical f=4kk+q -> stored q*8+kk: each read instruction
// (fixed q, kk=0..7) touches 8 consecutive float4s = all 32 banks once.
__device__ __forceinline__ int permf4(int f) { return ((f & 3) << 3) | (f >> 2); }
// Writer: output-pair slot s (floats 2s,2s+1) -> byte offset in buffer.
__device__ __forceinline__ int slot_byteoff(int s) {
  return permf4(s >> 1) * 16 + (s & 1) * 8;
}

// Per-t scalars: idx (int bits), fr, td, tsub
__global__ void prep0(const float* __restrict__ times, float4* __restrict__ si,
                      int* __restrict__ anyobs) {
  __shared__ float ts[TT];
  int t = threadIdx.x;
  ts[t] = times[t];
  __syncthreads();
  float tv = ts[t];
  int cnt = 0;
  for (int jj = 0; jj < TT; ++jj) cnt += (tv > ts[jj]) ? 1 : 0;
  int idx = cnt - 1;
  idx = min(max(idx, 0), TT - 2);
  float4 o;
  o.x = __int_as_float(idx);
  o.y = tv - ts[idx];
  o.z = (t == 0) ? 0.f : (tv - ts[t - 1]);
  o.w = (t == 0) ? ts[0] : ts[t - 1];
  si[t] = o;
  anyobs[t] = 0;
}

// obs[b,t] = max over diffed channels 1..32 > 0.5 ; anyobs[t] = OR over b
__global__ void prep_obs(const float* __restrict__ ca, const float* __restrict__ cb,
                         const float* __restrict__ cc2, const float* __restrict__ cd,
                         const float4* __restrict__ si, int* __restrict__ anyobs,
                         unsigned char* __restrict__ obs) {
  int grp = blockIdx.x * (blockDim.x >> 5) + (threadIdx.x >> 5);
  int lane = threadIdx.x & 31;
  int t = grp & (TT - 1);
  int b = grp / TT;
  int ch = 1 + lane;
  float4 s = si[t];
  int idx = __float_as_int(s.x);
  float fr = s.y;
  size_t base = ((size_t)b * (TT - 1) + idx) * CC + ch;
  float f3 = fr / 3.f;
  float v = ca[base] + (cb[base] + (0.5f * cc2[base] + cd[base] * f3) * fr) * fr;
  float D = v;
  if (t >= 1) {
    float4 sp = si[t - 1];
    int idxp = __float_as_int(sp.x);
    float frp = sp.y;
    size_t basep = ((size_t)b * (TT - 1) + idxp) * CC + ch;
    float f3p = frp / 3.f;
    float vp = ca[basep] + (cb[basep] + (0.5f * cc2[basep] + cd[basep] * f3p) * frp) * frp;
    D = v - vp;
  }
  float m = D;
  #pragma unroll
  for (int off = 16; off >= 1; off >>= 1) m = fmaxf(m, __shfl_xor(m, off));
  if (lane == 0) {
    unsigned char o = (m > 0.5f) ? (unsigned char)1 : (unsigned char)0;
    obs[(size_t)b * TT + t] = o;
    if (o) atomicOr(&anyobs[t], 1);
  }
}

// One block per batch element. 512 threads. Thread (wv, jslot=lane>>3, kk=lane&7)
// owns output pair j0 = wv*16 + jslot*2 over k-rows 16kk..16kk+15.
// Reduction over kk: 3 DPP row_shl adds (valid at kk==0, which also writes).
// launch_bounds(512,1): grid==256 gives 1 block/CU regardless; lift the VGPR
// cap so ALL weights stay register-resident (no in-loop L2 reloads).
__launch_bounds__(512, 1)
__global__ void ode_main(
    const float* __restrict__ ca, const float* __restrict__ cb,
    const float* __restrict__ cc2, const float* __restrict__ cd,
    const int* __restrict__ final_index,
    const float* __restrict__ Wr, const float* __restrict__ br,
    const float* __restrict__ Wz, const float* __restrict__ bz,
    const float* __restrict__ Wxn, const float* __restrict__ bxn,
    const float* __restrict__ Whn, const float* __restrict__ bhn,
    const float* __restrict__ Wode, const float* __restrict__ bode,
    const float* __restrict__ Wlin, const float* __restrict__ blin,
    const float4* __restrict__ si, const int* __restrict__ anyobs,
    const unsigned char* __restrict__ obsArr,
    float* __restrict__ out)
{
  __shared__ alignas(16) float hS[HID];
  __shared__ alignas(16) float vA[HID];
  __shared__ alignas(16) float vB[HID];
  __shared__ alignas(16) float xs[HALFC];
  __shared__ alignas(16) float4 siL[TT];
  __shared__ unsigned char flagL[TT];

  const int tid = threadIdx.x;
  const int b = blockIdx.x;
  const int lane = tid & 63;
  const int wv = tid >> 6;
  const int jslot = lane >> 3;   // 0..7
  const int kk = lane & 7;       // 0..7
  const int j0 = wv * 16 + jslot * 2;
  const int wroff = slot_byteoff(wv * 8 + jslot);

  // ---- weights in registers: w[2*i+m] = W[(16*kk+i)*HID + j0+m] ----
  float wode[32], whn[32], wrh[32], wzh[32];
  float wrx[8], wzx[8], wxn[8];
  #pragma unroll
  for (int i = 0; i < 16; ++i) {
    const int row = 16 * kk + i;
    float2 q;
    q = *(const float2*)&Wode[row * HID + j0]; wode[2*i] = q.x; wode[2*i+1] = q.y;
    q = *(const float2*)&Whn [row * HID + j0]; whn [2*i] = q.x; whn [2*i+1] = q.y;
    q = *(const float2*)&Wr[(HALFC + row) * HID + j0]; wrh[2*i] = q.x; wrh[2*i+1] = q.y;
    q = *(const float2*)&Wz[(HALFC + row) * HID + j0]; wzh[2*i] = q.x; wzh[2*i+1] = q.y;
  }
  #pragma unroll
  for (int i = 0; i < 4; ++i) {
    const int xrow = 4 * kk + i;
    float2 q;
    q = *(const float2*)&Wr [xrow * HID + j0]; wrx[2*i] = q.x; wrx[2*i+1] = q.y;
    q = *(const float2*)&Wz [xrow * HID + j0]; wzx[2*i] = q.x; wzx[2*i+1] = q.y;
    q = *(const float2*)&Wxn[xrow * HID + j0]; wxn[2*i] = q.x; wxn[2*i+1] = q.y;
  }
  float bo0, bo1, bh0, bh1, br0, br1, bz0, bz1, bx0, bx1;
  { float2 q;
    q = *(const float2*)&bode[j0]; bo0 = q.x; bo1 = q.y;
    q = *(const float2*)&bhn [j0]; bh0 = q.x; bh1 = q.y;
    q = *(const float2*)&br  [j0]; br0 = q.x; br1 = q.y;
    q = *(const float2*)&bz  [j0]; bz0 = q.x; bz1 = q.y;
    q = *(const float2*)&bxn [j0]; bx0 = q.x; bx1 = q.y;
  }
  const int fidx = final_index[b];

  // ---- stage per-step metadata into LDS (one-time) ----
  {
    siL[tid] = si[tid];
    const int ao = anyobs[tid];
    const unsigned char o = obsArr[(size_t)b * TT + tid];
    flagL[tid] = (unsigned char)((ao ? 1 : 0) | (o ? 2 : 0));
  }
  if (tid < HID) { hS[tid] = 0.f; vA[tid] = 0.f; vB[tid] = 0.f; }
  if (tid < HALFC) xs[tid] = 0.f;
  float hj0 = 0.f, hj1 = 0.f;  // valid on kk==0 lanes
  float dtv = 0.f;             // valid on tid==0
  block_sync_lds();

  // matvec over permuted LDS buffer: per-thread 16 k-rows x 2 outputs,
  // accumulator chains split 2x8 per output to shorten dep latency.
  auto mv = [&](const float* __restrict__ buf, const float (&w)[32],
                float& o0, float& o1) {
    const float4* b4 = (const float4*)buf;
    float vv[16];
    #pragma unroll
    for (int q = 0; q < 4; ++q) {
      const float4 x4 = b4[q * 8 + kk];
      vv[4*q] = x4.x; vv[4*q+1] = x4.y; vv[4*q+2] = x4.z; vv[4*q+3] = x4.w;
    }
    float a0 = 0.f, b0 = 0.f, a1 = 0.f, b1 = 0.f;
    #pragma unroll
    for (int i = 0; i < 8; ++i) {
      a0 = fmaf(vv[i],     w[2*i],       a0);
      a1 = fmaf(vv[i],     w[2*i+1],     a1);
      b0 = fmaf(vv[i + 8], w[2*(i+8)],   b0);
      b1 = fmaf(vv[i + 8], w[2*(i+8)+1], b1);
    }
    o0 = red8(a0 + b0);
    o1 = red8(a1 + b1);
  };

  float4 s = siL[0];
  int flg = flagL[0];

  for (int t = 0; ; ++t) {
    const int sidx = __float_as_int(s.x);
    const float fr = s.y, td = s.z, tsub = s.w;
    const bool apply = (flg & 1) && (flg & 2);

    // Issue x-coeff global loads early; they stay in flight across the raw
    // barriers (no vmcnt drain) and are waited just before the spline.
    float xa = 0.f, xb = 0.f, xc = 0.f, xd = 0.f;
    float ya = 0.f, yb = 0.f, yc = 0.f, yd = 0.f;
    if (tid < 32) {
      const size_t base = ((size_t)b * (TT - 1) + sidx) * CC;
      const int ch = 33 + tid;
      xa = ca[base + ch]; xb = cb[base + ch]; xc = cc2[base + ch]; xd = cd[base + ch];
      if (tid == 0) { ya = ca[base]; yb = cb[base]; yc = cc2[base]; yd = cd[base]; }
    }

    if (t > 0) {
      const float htd = 0.5f * td;
      float p0, p1, k0, k1, ks0, ks1;
      // stage 1: k1 = f(h)
      mv(hS, wode, p0, p1);
      k0 = ftanh(p0 + bo0); k1 = ftanh(p1 + bo1);
      ks0 = k0; ks1 = k1;
      if (kk == 0)
        *(float2*)((char*)vA + wroff) =
            make_float2(fmaf(htd, k0, hj0), fmaf(htd, k1, hj1));
      block_sync_lds();
      // stage 2: k2 = f(h + td/2 k1)
      mv(vA, wode, p0, p1);
      k0 = ftanh(p0 + bo0); k1 = ftanh(p1 + bo1);
      ks0 = fmaf(2.f, k0, ks0); ks1 = fmaf(2.f, k1, ks1);
      if (kk == 0)
        *(float2*)((char*)vB + wroff) =
            make_float2(fmaf(htd, k0, hj0), fmaf(htd, k1, hj1));
      block_sync_lds();
      // stage 3: k3 = f(h + td/2 k2)
      mv(vB, wode, p0, p1);
      k0 = ftanh(p0 + bo0); k1 = ftanh(p1 + bo1);
      ks0 = fmaf(2.f, k0, ks0); ks1 = fmaf(2.f, k1, ks1);
      if (kk == 0)
        *(float2*)((char*)vA + wroff) =
            make_float2(fmaf(td, k0, hj0), fmaf(td, k1, hj1));
      block_sync_lds();
      // stage 4: k4 = f(h + td k3); h += td/6 (k1+2k2+2k3+k4)
      mv(vA, wode, p0, p1);
      k0 = ftanh(p0 + bo0); k1 = ftanh(p1 + bo1);
      ks0 += k0; ks1 += k1;
      hj0 = fmaf(td * (1.f / 6.f), ks0, hj0);
      hj1 = fmaf(td * (1.f / 6.f), ks1, hj1);
      if (kk == 0)
        *(float2*)((char*)vB + wroff) = make_float2(hj0, hj1);
    }

    // Spline -> xs (tid<32). Wait for the global loads here (hidden under RK4).
    float xdelta = 0.f;
    vm_wait0();
    if (tid < 32) {
      const float f3 = fr * (1.f / 3.f);
      float sv = xa + (xb + (0.5f * xc + xd * f3) * fr) * fr;
      if (tid == 0) {
        const float s0 = ya + (yb + (0.5f * yc + yd * f3) * fr) * fr;
        xdelta = s0 - tsub;
        sv += dtv;  // Xp[:,0] += dt
      }
      xs[tid] = sv;
    }
    block_sync_lds();  // covers vB (evolved h) and xs

    // GRU
    {
      const float4* b4 = (const float4*)vB;
      float vv[16];
      #pragma unroll
      for (int q = 0; q < 4; ++q) {
        const float4 x4 = b4[q * 8 + kk];
        vv[4*q] = x4.x; vv[4*q+1] = x4.y; vv[4*q+2] = x4.z; vv[4*q+3] = x4.w;
      }
      float rp0 = 0.f, rp1 = 0.f, zp0 = 0.f, zp1 = 0.f;
      float gp0 = 0.f, gp1 = 0.f, xp0 = 0.f, xp1 = 0.f;
      #pragma unroll
      for (int i = 0; i < 16; ++i) {
        rp0 = fmaf(vv[i], wrh[2*i],   rp0); rp1 = fmaf(vv[i], wrh[2*i+1], rp1);
        zp0 = fmaf(vv[i], wzh[2*i],   zp0); zp1 = fmaf(vv[i], wzh[2*i+1], zp1);
        gp0 = fmaf(vv[i], whn[2*i],   gp0); gp1 = fmaf(vv[i], whn[2*i+1], gp1);
      }
      const float4 xq = ((const float4*)xs)[kk];
      const float xv[4] = {xq.x, xq.y, xq.z, xq.w};
      #pragma unroll
      for (int i = 0; i < 4; ++i) {
        rp0 = fmaf(xv[i], wrx[2*i],   rp0); rp1 = fmaf(xv[i], wrx[2*i+1], rp1);
        zp0 = fmaf(xv[i], wzx[2*i],   zp0); zp1 = fmaf(xv[i], wzx[2*i+1], zp1);
        xp0 = fmaf(xv[i], wxn[2*i],   xp0); xp1 = fmaf(xv[i], wxn[2*i+1], xp1);
      }
      rp0 = red8(rp0); rp1 = red8(rp1);
      zp0 = red8(zp0); zp1 = red8(zp1);
      gp0 = red8(gp0); gp1 = red8(gp1);
      xp0 = red8(xp0); xp1 = red8(xp1);
      // acts computed on all lanes; only kk==0's values are valid/stored
      const float r0 = fsig(rp0 + br0), r1 = fsig(rp1 + br1);
      const float z0 = fsig(zp0 + bz0), z1 = fsig(zp1 + bz1);
      const float n0 = ftanh(xp0 + bx0 + (gp0 + bh0) * r0);
      const float n1 = ftanh(xp1 + bx1 + (gp1 + bh1) * r1);
      const float h0n = fmaf(z0, hj0 - n0, n0);
      const float h1n = fmaf(z1, hj1 - n1, n1);
      hj0 = apply ? h0n : hj0;
      hj1 = apply ? h1n : hj1;
      if (kk == 0)
        *(float2*)((char*)hS + wroff) = make_float2(hj0, hj1);
    }
    if (tid == 0 && (flg & 1) && !(flg & 2)) dtv += xdelta;

    if (t == fidx) break;
    // prefetch next step's metadata from LDS
    const int tn = t + 1;
    s = siL[tn];
    flg = flagL[tn];
    block_sync_lds();  // hS visible for next stage 1
  }

  block_sync_lds();
  // final projection: out = h @ W_lin + b_lin (de-permute hS reads)
  if (tid < ODIM) {
    float acc = blin[tid];
    const float* hf = (const float*)hS;
    #pragma unroll 8
    for (int q = 0; q < HID; ++q) {
      const float hv = hf[permf4(q >> 2) * 4 + (q & 3)];
      acc = fmaf(hv, Wlin[q * ODIM + tid], acc);
    }
    out[b * ODIM + tid] = acc;
  }
}

extern "C" void kernel_launch(void* const* d_in, const int* in_sizes, int n_in,
                              void* d_out, int out_size, void* d_ws, size_t ws_size,
                              hipStream_t stream) {
  const float* times = (const float*)d_in[0];
  const float* ca   = (const float*)d_in[1];
  const float* cb   = (const float*)d_in[2];
  const float* cc2  = (const float*)d_in[3];
  const float* cd   = (const float*)d_in[4];
  const int*   fidx = (const int*)d_in[5];
  const float* Wr   = (const float*)d_in[6];
  const float* br   = (const float*)d_in[7];
  const float* Wz   = (const float*)d_in[8];
  const float* bz   = (const float*)d_in[9];
  const float* Wxn  = (const float*)d_in[10];
  const float* bxn  = (const float*)d_in[11];
  const float* Whn  = (const float*)d_in[12];
  const float* bhn  = (const float*)d_in[13];
  const float* Wode = (const float*)d_in[14];
  const float* bode = (const float*)d_in[15];
  const float* Wlin = (const float*)d_in[16];
  const float* blin = (const float*)d_in[17];
  float* out = (float*)d_out;

  char* ws = (char*)d_ws;
  float4* si = (float4*)ws;                                     // TT*16 B
  int* anyobs = (int*)(ws + TT * 16);                           // TT*4 B
  unsigned char* obs = (unsigned char*)(ws + TT * 16 + TT * 4); // BB*TT B

  prep0<<<1, TT, 0, stream>>>(times, si, anyobs);
  prep_obs<<<(BB * TT) / 8, 256, 0, stream>>>(ca, cb, cc2, cd, si, anyobs, obs);
  ode_main<<<BB, 512, 0, stream>>>(ca, cb, cc2, cd, fidx, Wr, br, Wz, bz,
                                   Wxn, bxn, Whn, bhn, Wode, bode, Wlin, blin,
                                   si, anyobs, obs, out);
}

// Round 11
// 1043.675 us; speedup vs baseline: 1.2762x; 1.0764x over previous
//
#include <hip/hip_runtime.h>
#include <string.h>

#define TT 512
#define BB 256
#define CC 65
#define HALFC 32
#define HID 128
#define ODIM 10

typedef _Float16 half2_t __attribute__((ext_vector_type(2)));

// tanh(x) = 2/(1+e^{-2x}) - 1
__device__ __forceinline__ float ftanh(float x) {
  float u = __builtin_amdgcn_exp2f(x * -2.885390082f);
  return fmaf(2.f, __builtin_amdgcn_rcpf(1.f + u), -1.f);
}
// sigmoid(x) = 1/(1+e^{-x})
__device__ __forceinline__ float fsig(float x) {
  float u = __builtin_amdgcn_exp2f(x * -1.442695041f);
  return __builtin_amdgcn_rcpf(1.f + u);
}

// pack two f32 -> half2 (v_cvt_pkrtz_f16_f32), bit-cast to our vector type
__device__ __forceinline__ half2_t h2cvt(float a, float b) {
  auto r = __builtin_amdgcn_cvt_pkrtz(a, b);
  half2_t o;
  memcpy(&o, &r, sizeof(o));
  return o;
}

__device__ __forceinline__ float fdot2h(half2_t a, half2_t b, float c) {
#if __has_builtin(__builtin_amdgcn_fdot2)
  return __builtin_amdgcn_fdot2(a, b, c, false);
#else
  float d;
  asm("v_dot2_f32_f16 %0, %1, %2, %3" : "=v"(d) : "v"(a), "v"(b), "v"(c));
  return d;
#endif
}

template <int CTRL>
__device__ __forceinline__ float dpp_add(float x) {
  return x + __int_as_float(__builtin_amdgcn_update_dpp(
      0, __float_as_int(x), CTRL, 0xF, 0xF, true));
}
// 8-lane subgroup sum via row_shl; valid at (lane&7)==0 (verified R5).
__device__ __forceinline__ float red8(float x) {
  x = dpp_add<0x101>(x);  // row_shl:1
  x = dpp_add<0x102>(x);  // row_shl:2
  x = dpp_add<0x104>(x);  // row_shl:4
  return x;
}

// Raw barrier: drain LDS ops, no vmcnt drain (global loads stay in flight).
__device__ __forceinline__ void block_sync_lds() {
  asm volatile("s_waitcnt lgkmcnt(0)" ::: "memory");
  __builtin_amdgcn_s_barrier();
  asm volatile("" ::: "memory");
}
__device__ __forceinline__ void vm_wait0() {
  asm volatile("s_waitcnt vmcnt(0)" ::: "memory");
}

// f16 LDS layout: 128 halfs = 16 b128 chunks of 8. Logical chunk c = 2kk+r
// stored at physical chunk p = (c&1)*8 + (c>>1) = r*8+kk. Lane kk reads
// physical chunks {kk, 8+kk} (= logical rows 16kk..16kk+15): one b128 read
// instruction spans physical chunks 0..7 -> all 8 bank groups, broadcast
// across the 8 jslot groups. Conflict-free.
__device__ __forceinline__ int h2_slot_byteoff(int s) {  // s = output pair 0..63
  const int c = s >> 2;                 // logical chunk of halfs 2s,2s+1
  const int p = ((c & 1) << 3) | (c >> 1);
  return p * 16 + (s & 3) * 4;
}

// Per-t scalars: idx (int bits), fr, td, tsub
__global__ void prep0(const float* __restrict__ times, float4* __restrict__ si,
                      int* __restrict__ anyobs) {
  __shared__ float ts[TT];
  int t = threadIdx.x;
  ts[t] = times[t];
  __syncthreads();
  float tv = ts[t];
  int cnt = 0;
  for (int jj = 0; jj < TT; ++jj) cnt += (tv > ts[jj]) ? 1 : 0;
  int idx = cnt - 1;
  idx = min(max(idx, 0), TT - 2);
  float4 o;
  o.x = __int_as_float(idx);
  o.y = tv - ts[idx];
  o.z = (t == 0) ? 0.f : (tv - ts[t - 1]);
  o.w = (t == 0) ? ts[0] : ts[t - 1];
  si[t] = o;
  anyobs[t] = 0;
}

// obs[b,t] = max over diffed channels 1..32 > 0.5 ; anyobs[t] = OR over b
__global__ void prep_obs(const float* __restrict__ ca, const float* __restrict__ cb,
                         const float* __restrict__ cc2, const float* __restrict__ cd,
                         const float4* __restrict__ si, int* __restrict__ anyobs,
                         unsigned char* __restrict__ obs) {
  int grp = blockIdx.x * (blockDim.x >> 5) + (threadIdx.x >> 5);
  int lane = threadIdx.x & 31;
  int t = grp & (TT - 1);
  int b = grp / TT;
  int ch = 1 + lane;
  float4 s = si[t];
  int idx = __float_as_int(s.x);
  float fr = s.y;
  size_t base = ((size_t)b * (TT - 1) + idx) * CC + ch;
  float f3 = fr / 3.f;
  float v = ca[base] + (cb[base] + (0.5f * cc2[base] + cd[base] * f3) * fr) * fr;
  float D = v;
  if (t >= 1) {
    float4 sp = si[t - 1];
    int idxp = __float_as_int(sp.x);
    float frp = sp.y;
    size_t basep = ((size_t)b * (TT - 1) + idxp) * CC + ch;
    float f3p = frp / 3.f;
    float vp = ca[basep] + (cb[basep] + (0.5f * cc2[basep] + cd[basep] * f3p) * frp) * frp;
    D = v - vp;
  }
  float m = D;
  #pragma unroll
  for (int off = 16; off >= 1; off >>= 1) m = fmaxf(m, __shfl_xor(m, off));
  if (lane == 0) {
    unsigned char o = (m > 0.5f) ? (unsigned char)1 : (unsigned char)0;
    obs[(size_t)b * TT + t] = o;
    if (o) atomicOr(&anyobs[t], 1);
  }
}

// One block per batch element. 512 threads. Thread (wv, jslot=lane>>3, kk=lane&7)
// owns output pair j0 = wv*16 + jslot*2 over k-rows 16kk..16kk+15.
// h-matvec weights packed f16 (v_dot2_f32_f16), h/v LDS buffers f16;
// x-path and master h stay fp32. Reduction: red8 (valid at kk==0).
__launch_bounds__(512, 1)
__global__ void ode_main(
    const float* __restrict__ ca, const float* __restrict__ cb,
    const float* __restrict__ cc2, const float* __restrict__ cd,
    const int* __restrict__ final_index,
    const float* __restrict__ Wr, const float* __restrict__ br,
    const float* __restrict__ Wz, const float* __restrict__ bz,
    const float* __restrict__ Wxn, const float* __restrict__ bxn,
    const float* __restrict__ Whn, const float* __restrict__ bhn,
    const float* __restrict__ Wode, const float* __restrict__ bode,
    const float* __restrict__ Wlin, const float* __restrict__ blin,
    const float4* __restrict__ si, const int* __restrict__ anyobs,
    const unsigned char* __restrict__ obsArr,
    float* __restrict__ out)
{
  __shared__ alignas(16) half2_t hS2[HID / 2];
  __shared__ alignas(16) half2_t vA2[HID / 2];
  __shared__ alignas(16) half2_t vB2[HID / 2];
  __shared__ alignas(16) float xs[HALFC];
  __shared__ alignas(16) float4 siL[TT];
  __shared__ unsigned char flagL[TT];

  const int tid = threadIdx.x;
  const int b = blockIdx.x;
  const int lane = tid & 63;
  const int wv = tid >> 6;
  const int jslot = lane >> 3;   // 0..7
  const int kk = lane & 7;       // 0..7
  const int j0 = wv * 16 + jslot * 2;
  const int spair = wv * 8 + jslot;
  const int wroff = h2_slot_byteoff(spair);

  // ---- h-matvec weights packed f16: w[2i+c] = (W[16kk+2i][j0+c], W[16kk+2i+1][j0+c])
  half2_t wodeH[16], whnH[16], wrhH[16], wzhH[16];
  #pragma unroll
  for (int i = 0; i < 8; ++i) {
    const int r0 = 16 * kk + 2 * i, r1 = r0 + 1;
    float2 q0, q1;
    q0 = *(const float2*)&Wode[r0 * HID + j0];
    q1 = *(const float2*)&Wode[r1 * HID + j0];
    wodeH[2*i]   = h2cvt(q0.x, q1.x);
    wodeH[2*i+1] = h2cvt(q0.y, q1.y);
    q0 = *(const float2*)&Whn[r0 * HID + j0];
    q1 = *(const float2*)&Whn[r1 * HID + j0];
    whnH[2*i]   = h2cvt(q0.x, q1.x);
    whnH[2*i+1] = h2cvt(q0.y, q1.y);
    q0 = *(const float2*)&Wr[(HALFC + r0) * HID + j0];
    q1 = *(const float2*)&Wr[(HALFC + r1) * HID + j0];
    wrhH[2*i]   = h2cvt(q0.x, q1.x);
    wrhH[2*i+1] = h2cvt(q0.y, q1.y);
    q0 = *(const float2*)&Wz[(HALFC + r0) * HID + j0];
    q1 = *(const float2*)&Wz[(HALFC + r1) * HID + j0];
    wzhH[2*i]   = h2cvt(q0.x, q1.x);
    wzhH[2*i+1] = h2cvt(q0.y, q1.y);
  }
  // x-part weights stay fp32 (xs magnitudes can be large via dt accumulation)
  float wrx[8], wzx[8], wxn[8];
  #pragma unroll
  for (int i = 0; i < 4; ++i) {
    const int xrow = 4 * kk + i;
    float2 q;
    q = *(const float2*)&Wr [xrow * HID + j0]; wrx[2*i] = q.x; wrx[2*i+1] = q.y;
    q = *(const float2*)&Wz [xrow * HID + j0]; wzx[2*i] = q.x; wzx[2*i+1] = q.y;
    q = *(const float2*)&Wxn[xrow * HID + j0]; wxn[2*i] = q.x; wxn[2*i+1] = q.y;
  }
  float bo0, bo1, bh0, bh1, br0, br1, bz0, bz1, bx0, bx1;
  { float2 q;
    q = *(const float2*)&bode[j0]; bo0 = q.x; bo1 = q.y;
    q = *(const float2*)&bhn [j0]; bh0 = q.x; bh1 = q.y;
    q = *(const float2*)&br  [j0]; br0 = q.x; br1 = q.y;
    q = *(const float2*)&bz  [j0]; bz0 = q.x; bz1 = q.y;
    q = *(const float2*)&bxn [j0]; bx0 = q.x; bx1 = q.y;
  }
  const int fidx = final_index[b];

  // ---- stage per-step metadata into LDS (one-time) ----
  {
    siL[tid] = si[tid];
    const int ao = anyobs[tid];
    const unsigned char o = obsArr[(size_t)b * TT + tid];
    flagL[tid] = (unsigned char)((ao ? 1 : 0) | (o ? 2 : 0));
  }
  if (tid < HID / 2) {
    const half2_t z2 = {(_Float16)0.f, (_Float16)0.f};
    hS2[tid] = z2; vA2[tid] = z2; vB2[tid] = z2;
  }
  if (tid < HALFC) xs[tid] = 0.f;
  float hj0 = 0.f, hj1 = 0.f;  // fp32 master h, valid on kk==0 lanes
  float dtv = 0.f;             // valid on tid==0
  block_sync_lds();

  // matvec over f16 LDS buffer: lane kk reads physical chunks kk and 8+kk
  // (= logical k-rows 16kk..16kk+15) as 8 half2 pairs; 16 dot2 per 2 outputs.
  auto mv = [&](const half2_t* __restrict__ buf, const half2_t (&w)[16],
                float& o0, float& o1) {
    half2_t v2[8];
    #pragma unroll
    for (int i = 0; i < 4; ++i) {
      v2[i]     = buf[4 * kk + i];
      v2[4 + i] = buf[32 + 4 * kk + i];
    }
    float a0 = 0.f, a1 = 0.f, b0 = 0.f, b1 = 0.f;
    #pragma unroll
    for (int i = 0; i < 4; ++i) {
      a0 = fdot2h(v2[i],     w[2*i],       a0);
      a1 = fdot2h(v2[i],     w[2*i+1],     a1);
      b0 = fdot2h(v2[4 + i], w[2*(4+i)],   b0);
      b1 = fdot2h(v2[4 + i], w[2*(4+i)+1], b1);
    }
    o0 = red8(a0 + b0);
    o1 = red8(a1 + b1);
  };

  float4 s = siL[0];
  int flg = flagL[0];

  for (int t = 0; ; ++t) {
    const int sidx = __float_as_int(s.x);
    const float fr = s.y, td = s.z, tsub = s.w;
    const bool apply = (flg & 1) && (flg & 2);

    // Issue x-coeff global loads early; stay in flight across raw barriers.
    float xa = 0.f, xb = 0.f, xc = 0.f, xd = 0.f;
    float ya = 0.f, yb = 0.f, yc = 0.f, yd = 0.f;
    if (tid < 32) {
      const size_t base = ((size_t)b * (TT - 1) + sidx) * CC;
      const int ch = 33 + tid;
      xa = ca[base + ch]; xb = cb[base + ch]; xc = cc2[base + ch]; xd = cd[base + ch];
      if (tid == 0) { ya = ca[base]; yb = cb[base]; yc = cc2[base]; yd = cd[base]; }
    }

    if (t > 0) {
      const float htd = 0.5f * td;
      float p0, p1, k0, k1, ks0, ks1;
      // stage 1: k1 = f(h)
      mv(hS2, wodeH, p0, p1);
      k0 = ftanh(p0 + bo0); k1 = ftanh(p1 + bo1);
      ks0 = k0; ks1 = k1;
      if (kk == 0)
        *(half2_t*)((char*)vA2 + wroff) =
            h2cvt(fmaf(htd, k0, hj0), fmaf(htd, k1, hj1));
      block_sync_lds();
      // stage 2: k2 = f(h + td/2 k1)
      mv(vA2, wodeH, p0, p1);
      k0 = ftanh(p0 + bo0); k1 = ftanh(p1 + bo1);
      ks0 = fmaf(2.f, k0, ks0); ks1 = fmaf(2.f, k1, ks1);
      if (kk == 0)
        *(half2_t*)((char*)vB2 + wroff) =
            h2cvt(fmaf(htd, k0, hj0), fmaf(htd, k1, hj1));
      block_sync_lds();
      // stage 3: k3 = f(h + td/2 k2)
      mv(vB2, wodeH, p0, p1);
      k0 = ftanh(p0 + bo0); k1 = ftanh(p1 + bo1);
      ks0 = fmaf(2.f, k0, ks0); ks1 = fmaf(2.f, k1, ks1);
      if (kk == 0)
        *(half2_t*)((char*)vA2 + wroff) =
            h2cvt(fmaf(td, k0, hj0), fmaf(td, k1, hj1));
      block_sync_lds();
      // stage 4: k4 = f(h + td k3); h += td/6 (k1+2k2+2k3+k4)
      mv(vA2, wodeH, p0, p1);
      k0 = ftanh(p0 + bo0); k1 = ftanh(p1 + bo1);
      ks0 += k0; ks1 += k1;
      hj0 = fmaf(td * (1.f / 6.f), ks0, hj0);
      hj1 = fmaf(td * (1.f / 6.f), ks1, hj1);
      if (kk == 0)
        *(half2_t*)((char*)vB2 + wroff) = h2cvt(hj0, hj1);
    }

    // Spline -> xs (tid<32, fp32). Wait for global loads (hidden under RK4).
    float xdelta = 0.f;
    vm_wait0();
    if (tid < 32) {
      const float f3 = fr * (1.f / 3.f);
      float sv = xa + (xb + (0.5f * xc + xd * f3) * fr) * fr;
      if (tid == 0) {
        const float s0 = ya + (yb + (0.5f * yc + yd * f3) * fr) * fr;
        xdelta = s0 - tsub;
        sv += dtv;  // Xp[:,0] += dt
      }
      xs[tid] = sv;
    }
    block_sync_lds();  // covers vB2 (evolved h) and xs

    // GRU
    {
      half2_t v2[8];
      #pragma unroll
      for (int i = 0; i < 4; ++i) {
        v2[i]     = vB2[4 * kk + i];
        v2[4 + i] = vB2[32 + 4 * kk + i];
      }
      float rp0 = 0.f, rp1 = 0.f, zp0 = 0.f, zp1 = 0.f, gp0 = 0.f, gp1 = 0.f;
      #pragma unroll
      for (int i = 0; i < 8; ++i) {
        rp0 = fdot2h(v2[i], wrhH[2*i],   rp0);
        rp1 = fdot2h(v2[i], wrhH[2*i+1], rp1);
        zp0 = fdot2h(v2[i], wzhH[2*i],   zp0);
        zp1 = fdot2h(v2[i], wzhH[2*i+1], zp1);
        gp0 = fdot2h(v2[i], whnH[2*i],   gp0);
        gp1 = fdot2h(v2[i], whnH[2*i+1], gp1);
      }
      float xp0 = 0.f, xp1 = 0.f;
      const float4 xq = ((const float4*)xs)[kk];
      const float xv[4] = {xq.x, xq.y, xq.z, xq.w};
      #pragma unroll
      for (int i = 0; i < 4; ++i) {
        rp0 = fmaf(xv[i], wrx[2*i],   rp0); rp1 = fmaf(xv[i], wrx[2*i+1], rp1);
        zp0 = fmaf(xv[i], wzx[2*i],   zp0); zp1 = fmaf(xv[i], wzx[2*i+1], zp1);
        xp0 = fmaf(xv[i], wxn[2*i],   xp0); xp1 = fmaf(xv[i], wxn[2*i+1], xp1);
      }
      rp0 = red8(rp0); rp1 = red8(rp1);
      zp0 = red8(zp0); zp1 = red8(zp1);
      gp0 = red8(gp0); gp1 = red8(gp1);
      xp0 = red8(xp0); xp1 = red8(xp1);
      // acts computed on all lanes; only kk==0's values are valid/stored
      const float r0 = fsig(rp0 + br0), r1 = fsig(rp1 + br1);
      const float z0 = fsig(zp0 + bz0), z1 = fsig(zp1 + bz1);
      const float n0 = ftanh(xp0 + bx0 + (gp0 + bh0) * r0);
      const float n1 = ftanh(xp1 + bx1 + (gp1 + bh1) * r1);
      const float h0n = fmaf(z0, hj0 - n0, n0);
      const float h1n = fmaf(z1, hj1 - n1, n1);
      hj0 = apply ? h0n : hj0;
      hj1 = apply ? h1n : hj1;
      if (kk == 0)
        *(half2_t*)((char*)hS2 + wroff) = h2cvt(hj0, hj1);
    }
    if (tid == 0 && (flg & 1) && !(flg & 2)) dtv += xdelta;

    if (t == fidx) break;
    // prefetch next step's metadata from LDS
    const int tn = t + 1;
    s = siL[tn];
    flg = flagL[tn];
    block_sync_lds();  // hS2 visible for next stage 1
  }

  block_sync_lds();
  // final projection: out = h @ W_lin + b_lin (de-permute f16 hS2 reads)
  if (tid < ODIM) {
    float acc = blin[tid];
    const _Float16* hf = (const _Float16*)hS2;
    #pragma unroll 8
    for (int q = 0; q < HID; ++q) {
      const int cq = q >> 3;
      const int p = ((cq & 1) << 3) | (cq >> 1);
      const float hv = (float)hf[p * 8 + (q & 7)];
      acc = fmaf(hv, Wlin[q * ODIM + tid], acc);
    }
    out[b * ODIM + tid] = acc;
  }
}

extern "C" void kernel_launch(void* const* d_in, const int* in_sizes, int n_in,
                              void* d_out, int out_size, void* d_ws, size_t ws_size,
                              hipStream_t stream) {
  const float* times = (const float*)d_in[0];
  const float* ca   = (const float*)d_in[1];
  const float* cb   = (const float*)d_in[2];
  const float* cc2  = (const float*)d_in[3];
  const float* cd   = (const float*)d_in[4];
  const int*   fidx = (const int*)d_in[5];
  const float* Wr   = (const float*)d_in[6];
  const float* br   = (const float*)d_in[7];
  const float* Wz   = (const float*)d_in[8];
  const float* bz   = (const float*)d_in[9];
  const float* Wxn  = (const float*)d_in[10];
  const float* bxn  = (const float*)d_in[11];
  const float* Whn  = (const float*)d_in[12];
  const float* bhn  = (const float*)d_in[13];
  const float* Wode = (const float*)d_in[14];
  const float* bode = (const float*)d_in[15];
  const float* Wlin = (const float*)d_in[16];
  const float* blin = (const float*)d_in[17];
  float* out = (float*)d_out;

  char* ws = (char*)d_ws;
  float4* si = (float4*)ws;                                     // TT*16 B
  int* anyobs = (int*)(ws + TT * 16);                           // TT*4 B
  unsigned char* obs = (unsigned char*)(ws + TT * 16 + TT * 4); // BB*TT B

  prep0<<<1, TT, 0, stream>>>(times, si, anyobs);
  prep_obs<<<(BB * TT) / 8, 256, 0, stream>>>(ca, cb, cc2, cd, si, anyobs, obs);
  ode_main<<<BB, 512, 0, stream>>>(ca, cb, cc2, cd, fidx, Wr, br, Wz, bz,
                                   Wxn, bxn, Whn, bhn, Wode, bode, Wlin, blin,
                                   si, anyobs, obs, out);
}

// Round 12
// 956.825 us; speedup vs baseline: 1.3921x; 1.0908x over previous
//
#include <hip/hip_runtime.h>
#include <string.h>

#define TT 512
#define BB 256
#define CC 65
#define HALFC 32
#define HID 128
#define ODIM 10

typedef _Float16 half2_t __attribute__((ext_vector_type(2)));
typedef _Float16 half8_t __attribute__((ext_vector_type(8)));

// tanh(x) = 2/(1+e^{-2x}) - 1
__device__ __forceinline__ float ftanh(float x) {
  float u = __builtin_amdgcn_exp2f(x * -2.885390082f);
  return fmaf(2.f, __builtin_amdgcn_rcpf(1.f + u), -1.f);
}
// sigmoid(x) = 1/(1+e^{-x})
__device__ __forceinline__ float fsig(float x) {
  float u = __builtin_amdgcn_exp2f(x * -1.442695041f);
  return __builtin_amdgcn_rcpf(1.f + u);
}

// pack two f32 -> half2 (v_cvt_pkrtz_f16_f32)
__device__ __forceinline__ half2_t h2cvt(float a, float b) {
  auto r = __builtin_amdgcn_cvt_pkrtz(a, b);
  half2_t o;
  memcpy(&o, &r, sizeof(o));
  return o;
}

__device__ __forceinline__ float fdot2h(half2_t a, half2_t b, float c) {
  return __builtin_amdgcn_fdot2(a, b, c, false);
}

template <int CTRL>
__device__ __forceinline__ float dpp_add(float x) {
  return x + __int_as_float(__builtin_amdgcn_update_dpp(
      0, __float_as_int(x), CTRL, 0xF, 0xF, true));
}
// 4-lane subgroup sum via row_shl (verified direction, R5): dest[i] =
// sum src[i..i+3]; valid where (lane&3)==0 (lane 4p pulls 4p+1..4p+3,
// all within the same DPP 16-row).
__device__ __forceinline__ float red4(float x) {
  x = dpp_add<0x101>(x);  // row_shl:1
  x = dpp_add<0x102>(x);  // row_shl:2
  return x;
}

// Raw barrier: drain LDS ops, no vmcnt drain (global loads stay in flight).
__device__ __forceinline__ void block_sync_lds() {
  asm volatile("s_waitcnt lgkmcnt(0)" ::: "memory");
  __builtin_amdgcn_s_barrier();
  asm volatile("" ::: "memory");
}
__device__ __forceinline__ void vm_wait0() {
  asm volatile("s_waitcnt vmcnt(0)" ::: "memory");
}

// Per-t scalars: idx (int bits), fr, td, tsub
__global__ void prep0(const float* __restrict__ times, float4* __restrict__ si,
                      int* __restrict__ anyobs) {
  __shared__ float ts[TT];
  int t = threadIdx.x;
  ts[t] = times[t];
  __syncthreads();
  float tv = ts[t];
  int cnt = 0;
  for (int jj = 0; jj < TT; ++jj) cnt += (tv > ts[jj]) ? 1 : 0;
  int idx = cnt - 1;
  idx = min(max(idx, 0), TT - 2);
  float4 o;
  o.x = __int_as_float(idx);
  o.y = tv - ts[idx];
  o.z = (t == 0) ? 0.f : (tv - ts[t - 1]);
  o.w = (t == 0) ? ts[0] : ts[t - 1];
  si[t] = o;
  anyobs[t] = 0;
}

// obs[b,t] = max over diffed channels 1..32 > 0.5 ; anyobs[t] = OR over b
__global__ void prep_obs(const float* __restrict__ ca, const float* __restrict__ cb,
                         const float* __restrict__ cc2, const float* __restrict__ cd,
                         const float4* __restrict__ si, int* __restrict__ anyobs,
                         unsigned char* __restrict__ obs) {
  int grp = blockIdx.x * (blockDim.x >> 5) + (threadIdx.x >> 5);
  int lane = threadIdx.x & 31;
  int t = grp & (TT - 1);
  int b = grp / TT;
  int ch = 1 + lane;
  float4 s = si[t];
  int idx = __float_as_int(s.x);
  float fr = s.y;
  size_t base = ((size_t)b * (TT - 1) + idx) * CC + ch;
  float f3 = fr / 3.f;
  float v = ca[base] + (cb[base] + (0.5f * cc2[base] + cd[base] * f3) * fr) * fr;
  float D = v;
  if (t >= 1) {
    float4 sp = si[t - 1];
    int idxp = __float_as_int(sp.x);
    float frp = sp.y;
    size_t basep = ((size_t)b * (TT - 1) + idxp) * CC + ch;
    float f3p = frp / 3.f;
    float vp = ca[basep] + (cb[basep] + (0.5f * cc2[basep] + cd[basep] * f3p) * frp) * frp;
    D = v - vp;
  }
  float m = D;
  #pragma unroll
  for (int off = 16; off >= 1; off >>= 1) m = fmaxf(m, __shfl_xor(m, off));
  if (lane == 0) {
    unsigned char o = (m > 0.5f) ? (unsigned char)1 : (unsigned char)0;
    obs[(size_t)b * TT + t] = o;
    if (o) atomicOr(&anyobs[t], 1);
  }
}

// One block per batch element. 256 threads = 4 waves (1/SIMD; small barrier
// domain). Lane (p=lane>>2, kk=lane&3) owns output pair s = wv*16+p
// (outputs j0=2s, j0+1) over k-slice [32kk, 32kk+32). f16 weights+state
// via v_dot2_f32_f16; x channel 0 (dt channel, large) handled in f32.
// LDS vector layout LINEAR (64 half2): writes 16 banks/wave, reads 4-addr
// broadcast b128 — conflict-free by construction.
__launch_bounds__(256, 1)
__global__ void ode_main(
    const float* __restrict__ ca, const float* __restrict__ cb,
    const float* __restrict__ cc2, const float* __restrict__ cd,
    const int* __restrict__ final_index,
    const float* __restrict__ Wr, const float* __restrict__ br,
    const float* __restrict__ Wz, const float* __restrict__ bz,
    const float* __restrict__ Wxn, const float* __restrict__ bxn,
    const float* __restrict__ Whn, const float* __restrict__ bhn,
    const float* __restrict__ Wode, const float* __restrict__ bode,
    const float* __restrict__ Wlin, const float* __restrict__ blin,
    const float4* __restrict__ si, const int* __restrict__ anyobs,
    const unsigned char* __restrict__ obsArr,
    float* __restrict__ out)
{
  __shared__ alignas(16) half2_t hS2[HID / 2];
  __shared__ alignas(16) half2_t vA2[HID / 2];
  __shared__ alignas(16) half2_t vB2[HID / 2];
  __shared__ alignas(16) _Float16 xh[HALFC];
  __shared__ float xs0f;
  __shared__ alignas(16) float4 siL[TT];
  __shared__ unsigned char flagL[TT];

  const int tid = threadIdx.x;
  const int b = blockIdx.x;
  const int lane = tid & 63;
  const int wv = tid >> 6;       // 0..3
  const int p = lane >> 2;       // 0..15
  const int kk = lane & 3;       // 0..3
  const int s = wv * 16 + p;     // output pair 0..63
  const int j0 = 2 * s;
  const int wbyte = 4 * s;       // write byte offset (half2)

  // ---- h-matvec weights f16: w[2i+e] = (W[32kk+2i][j0+e], W[32kk+2i+1][j0+e])
  half2_t wodeH[32], whnH[32], wrhH[32], wzhH[32];
  #pragma unroll
  for (int i = 0; i < 16; ++i) {
    const int r0 = 32 * kk + 2 * i, r1 = r0 + 1;
    float2 q0, q1;
    q0 = *(const float2*)&Wode[r0 * HID + j0];
    q1 = *(const float2*)&Wode[r1 * HID + j0];
    wodeH[2*i] = h2cvt(q0.x, q1.x); wodeH[2*i+1] = h2cvt(q0.y, q1.y);
    q0 = *(const float2*)&Whn[r0 * HID + j0];
    q1 = *(const float2*)&Whn[r1 * HID + j0];
    whnH[2*i] = h2cvt(q0.x, q1.x); whnH[2*i+1] = h2cvt(q0.y, q1.y);
    q0 = *(const float2*)&Wr[(HALFC + r0) * HID + j0];
    q1 = *(const float2*)&Wr[(HALFC + r1) * HID + j0];
    wrhH[2*i] = h2cvt(q0.x, q1.x); wrhH[2*i+1] = h2cvt(q0.y, q1.y);
    q0 = *(const float2*)&Wz[(HALFC + r0) * HID + j0];
    q1 = *(const float2*)&Wz[(HALFC + r1) * HID + j0];
    wzhH[2*i] = h2cvt(q0.x, q1.x); wzhH[2*i+1] = h2cvt(q0.y, q1.y);
  }
  // x-part weights f16 over channels [8kk, 8kk+8): [i] out j0, [4+i] out j0+1
  half2_t wrxH[8], wzxH[8], wxnH[8];
  #pragma unroll
  for (int i = 0; i < 4; ++i) {
    const int c0 = 8 * kk + 2 * i, c1 = c0 + 1;
    float2 q0, q1;
    q0 = *(const float2*)&Wr[c0 * HID + j0];
    q1 = *(const float2*)&Wr[c1 * HID + j0];
    wrxH[i] = h2cvt(q0.x, q1.x); wrxH[4+i] = h2cvt(q0.y, q1.y);
    q0 = *(const float2*)&Wz[c0 * HID + j0];
    q1 = *(const float2*)&Wz[c1 * HID + j0];
    wzxH[i] = h2cvt(q0.x, q1.x); wzxH[4+i] = h2cvt(q0.y, q1.y);
    q0 = *(const float2*)&Wxn[c0 * HID + j0];
    q1 = *(const float2*)&Wxn[c1 * HID + j0];
    wxnH[i] = h2cvt(q0.x, q1.x); wxnH[4+i] = h2cvt(q0.y, q1.y);
  }
  // channel 0 (dt channel, large magnitude): zero its f16 weight, add in f32
  float wr0a = 0.f, wr0b = 0.f, wz0a = 0.f, wz0b = 0.f, wx0a = 0.f, wx0b = 0.f;
  if (kk == 0) {
    wrxH[0][0] = (_Float16)0.f; wrxH[4][0] = (_Float16)0.f;
    wzxH[0][0] = (_Float16)0.f; wzxH[4][0] = (_Float16)0.f;
    wxnH[0][0] = (_Float16)0.f; wxnH[4][0] = (_Float16)0.f;
    wr0a = Wr[j0];  wr0b = Wr[j0 + 1];
    wz0a = Wz[j0];  wz0b = Wz[j0 + 1];
    wx0a = Wxn[j0]; wx0b = Wxn[j0 + 1];
  }
  float bo0, bo1, bh0, bh1, br0, br1, bz0, bz1, bx0, bx1;
  { float2 q;
    q = *(const float2*)&bode[j0]; bo0 = q.x; bo1 = q.y;
    q = *(const float2*)&bhn [j0]; bh0 = q.x; bh1 = q.y;
    q = *(const float2*)&br  [j0]; br0 = q.x; br1 = q.y;
    q = *(const float2*)&bz  [j0]; bz0 = q.x; bz1 = q.y;
    q = *(const float2*)&bxn [j0]; bx0 = q.x; bx1 = q.y;
  }
  const int fidx = final_index[b];

  // ---- stage per-step metadata into LDS (one-time; 2 sweeps of 256) ----
  #pragma unroll
  for (int it = 0; it < 2; ++it) {
    const int tt = tid + it * 256;
    siL[tt] = si[tt];
    const int ao = anyobs[tt];
    const unsigned char o = obsArr[(size_t)b * TT + tt];
    flagL[tt] = (unsigned char)((ao ? 1 : 0) | (o ? 2 : 0));
  }
  if (tid < HID / 2) {
    const half2_t z2 = {(_Float16)0.f, (_Float16)0.f};
    hS2[tid] = z2; vA2[tid] = z2; vB2[tid] = z2;
  }
  if (tid < HALFC) xh[tid] = (_Float16)0.f;
  if (tid == 0) xs0f = 0.f;
  float hj0 = 0.f, hj1 = 0.f;  // fp32 master h, valid on kk==0 lanes
  float dtv = 0.f;             // valid on tid==0
  block_sync_lds();

  // matvec over linear f16 LDS vector: lane reads bytes [64kk, 64kk+64)
  // as 4 b128 (4-addr broadcast), 32 dot2 for 2 outputs, red4.
  auto mv = [&](const half2_t* __restrict__ buf, const half2_t (&w)[32],
                float& o0, float& o1) {
    half2_t v2[16];
    #pragma unroll
    for (int q = 0; q < 4; ++q) {
      const half8_t x8 = *(const half8_t*)((const char*)buf + 64 * kk + 16 * q);
      v2[4*q+0] = __builtin_shufflevector(x8, x8, 0, 1);
      v2[4*q+1] = __builtin_shufflevector(x8, x8, 2, 3);
      v2[4*q+2] = __builtin_shufflevector(x8, x8, 4, 5);
      v2[4*q+3] = __builtin_shufflevector(x8, x8, 6, 7);
    }
    float a0 = 0.f, a1 = 0.f, b0 = 0.f, b1 = 0.f;
    #pragma unroll
    for (int i = 0; i < 8; ++i) {
      a0 = fdot2h(v2[i],     w[2*i],       a0);
      a1 = fdot2h(v2[i],     w[2*i+1],     a1);
      b0 = fdot2h(v2[8 + i], w[2*(8+i)],   b0);
      b1 = fdot2h(v2[8 + i], w[2*(8+i)+1], b1);
    }
    o0 = red4(a0 + b0);
    o1 = red4(a1 + b1);
  };

  float4 sv4 = siL[0];
  int flg = flagL[0];

  for (int t = 0; ; ++t) {
    const int sidx = __float_as_int(sv4.x);
    const float fr = sv4.y, td = sv4.z, tsub = sv4.w;
    const bool apply = (flg & 1) && (flg & 2);

    // x-coeff global loads: lanes 0..7 of each wave own channels wv*8+lane.
    // Issued early; in flight across raw barriers; waited before spline.
    const int xch = wv * 8 + lane;       // valid when lane < 8
    const bool xlane = (lane < 8);
    float xa = 0.f, xb = 0.f, xc = 0.f, xd = 0.f;
    float ya = 0.f, yb = 0.f, yc = 0.f, yd = 0.f;
    if (xlane) {
      const size_t base = ((size_t)b * (TT - 1) + sidx) * CC;
      const int ch = 33 + xch;
      xa = ca[base + ch]; xb = cb[base + ch]; xc = cc2[base + ch]; xd = cd[base + ch];
      if (tid == 0) { ya = ca[base]; yb = cb[base]; yc = cc2[base]; yd = cd[base]; }
    }

    if (t > 0) {
      const float htd = 0.5f * td;
      float p0, p1, k0, k1, ks0, ks1;
      // stage 1: k1 = f(h)
      mv(hS2, wodeH, p0, p1);
      k0 = ftanh(p0 + bo0); k1 = ftanh(p1 + bo1);
      ks0 = k0; ks1 = k1;
      if (kk == 0)
        *(half2_t*)((char*)vA2 + wbyte) =
            h2cvt(fmaf(htd, k0, hj0), fmaf(htd, k1, hj1));
      block_sync_lds();
      // stage 2: k2 = f(h + td/2 k1)
      mv(vA2, wodeH, p0, p1);
      k0 = ftanh(p0 + bo0); k1 = ftanh(p1 + bo1);
      ks0 = fmaf(2.f, k0, ks0); ks1 = fmaf(2.f, k1, ks1);
      if (kk == 0)
        *(half2_t*)((char*)vB2 + wbyte) =
            h2cvt(fmaf(htd, k0, hj0), fmaf(htd, k1, hj1));
      block_sync_lds();
      // stage 3: k3 = f(h + td/2 k2)
      mv(vB2, wodeH, p0, p1);
      k0 = ftanh(p0 + bo0); k1 = ftanh(p1 + bo1);
      ks0 = fmaf(2.f, k0, ks0); ks1 = fmaf(2.f, k1, ks1);
      if (kk == 0)
        *(half2_t*)((char*)vA2 + wbyte) =
            h2cvt(fmaf(td, k0, hj0), fmaf(td, k1, hj1));
      block_sync_lds();
      // stage 4: k4 = f(h + td k3); h += td/6 (k1+2k2+2k3+k4)
      mv(vA2, wodeH, p0, p1);
      k0 = ftanh(p0 + bo0); k1 = ftanh(p1 + bo1);
      ks0 += k0; ks1 += k1;
      hj0 = fmaf(td * (1.f / 6.f), ks0, hj0);
      hj1 = fmaf(td * (1.f / 6.f), ks1, hj1);
      if (kk == 0)
        *(half2_t*)((char*)vB2 + wbyte) = h2cvt(hj0, hj1);
    }

    // Spline -> xh/xs0f. Wait for global loads here (hidden under RK4).
    float xdelta = 0.f;
    vm_wait0();
    if (xlane) {
      const float f3 = fr * (1.f / 3.f);
      float sv = xa + (xb + (0.5f * xc + xd * f3) * fr) * fr;
      if (tid == 0) {
        const float s0 = ya + (yb + (0.5f * yc + yd * f3) * fr) * fr;
        xdelta = s0 - tsub;
        sv += dtv;       // Xp[:,0] += dt
        xs0f = sv;       // f32 copy of channel 0
      }
      xh[xch] = (_Float16)sv;
    }
    block_sync_lds();  // covers vB2 (evolved h), xh, xs0f

    // GRU
    {
      half2_t v2[16];
      #pragma unroll
      for (int q = 0; q < 4; ++q) {
        const half8_t x8 = *(const half8_t*)((const char*)vB2 + 64 * kk + 16 * q);
        v2[4*q+0] = __builtin_shufflevector(x8, x8, 0, 1);
        v2[4*q+1] = __builtin_shufflevector(x8, x8, 2, 3);
        v2[4*q+2] = __builtin_shufflevector(x8, x8, 4, 5);
        v2[4*q+3] = __builtin_shufflevector(x8, x8, 6, 7);
      }
      float rp0 = 0.f, rp1 = 0.f, zp0 = 0.f, zp1 = 0.f, gp0 = 0.f, gp1 = 0.f;
      #pragma unroll
      for (int i = 0; i < 16; ++i) {
        rp0 = fdot2h(v2[i], wrhH[2*i],   rp0);
        rp1 = fdot2h(v2[i], wrhH[2*i+1], rp1);
        zp0 = fdot2h(v2[i], wzhH[2*i],   zp0);
        zp1 = fdot2h(v2[i], wzhH[2*i+1], zp1);
        gp0 = fdot2h(v2[i], whnH[2*i],   gp0);
        gp1 = fdot2h(v2[i], whnH[2*i+1], gp1);
      }
      float xp0 = 0.f, xp1 = 0.f;
      {
        const half8_t x8 = *(const half8_t*)((const char*)xh + 16 * kk);
        half2_t xv2[4];
        xv2[0] = __builtin_shufflevector(x8, x8, 0, 1);
        xv2[1] = __builtin_shufflevector(x8, x8, 2, 3);
        xv2[2] = __builtin_shufflevector(x8, x8, 4, 5);
        xv2[3] = __builtin_shufflevector(x8, x8, 6, 7);
        #pragma unroll
        for (int i = 0; i < 4; ++i) {
          rp0 = fdot2h(xv2[i], wrxH[i],   rp0);
          rp1 = fdot2h(xv2[i], wrxH[4+i], rp1);
          zp0 = fdot2h(xv2[i], wzxH[i],   zp0);
          zp1 = fdot2h(xv2[i], wzxH[4+i], zp1);
          xp0 = fdot2h(xv2[i], wxnH[i],   xp0);
          xp1 = fdot2h(xv2[i], wxnH[4+i], xp1);
        }
      }
      if (kk == 0) {
        const float x0 = xs0f;
        rp0 = fmaf(x0, wr0a, rp0); rp1 = fmaf(x0, wr0b, rp1);
        zp0 = fmaf(x0, wz0a, zp0); zp1 = fmaf(x0, wz0b, zp1);
        xp0 = fmaf(x0, wx0a, xp0); xp1 = fmaf(x0, wx0b, xp1);
      }
      rp0 = red4(rp0); rp1 = red4(rp1);
      zp0 = red4(zp0); zp1 = red4(zp1);
      gp0 = red4(gp0); gp1 = red4(gp1);
      xp0 = red4(xp0); xp1 = red4(xp1);
      // acts on all lanes; only kk==0's values are valid/stored
      const float r0 = fsig(rp0 + br0), r1 = fsig(rp1 + br1);
      const float z0 = fsig(zp0 + bz0), z1 = fsig(zp1 + bz1);
      const float n0 = ftanh(xp0 + bx0 + (gp0 + bh0) * r0);
      const float n1 = ftanh(xp1 + bx1 + (gp1 + bh1) * r1);
      const float h0n = fmaf(z0, hj0 - n0, n0);
      const float h1n = fmaf(z1, hj1 - n1, n1);
      hj0 = apply ? h0n : hj0;
      hj1 = apply ? h1n : hj1;
      if (kk == 0)
        *(half2_t*)((char*)hS2 + wbyte) = h2cvt(hj0, hj1);
    }
    if (tid == 0 && (flg & 1) && !(flg & 2)) dtv += xdelta;

    if (t == fidx) break;
    // prefetch next step's metadata from LDS
    const int tn = t + 1;
    sv4 = siL[tn];
    flg = flagL[tn];
    block_sync_lds();  // hS2 visible for next stage 1
  }

  block_sync_lds();
  // final projection: out = h @ W_lin + b_lin (hS2 is LINEAR: half j at index j)
  if (tid < ODIM) {
    float acc = blin[tid];
    const _Float16* hf = (const _Float16*)hS2;
    #pragma unroll 8
    for (int q = 0; q < HID; ++q) {
      const float hv = (float)hf[q];
      acc = fmaf(hv, Wlin[q * ODIM + tid], acc);
    }
    out[b * ODIM + tid] = acc;
  }
}

extern "C" void kernel_launch(void* const* d_in, const int* in_sizes, int n_in,
                              void* d_out, int out_size, void* d_ws, size_t ws_size,
                              hipStream_t stream) {
  const float* times = (const float*)d_in[0];
  const float* ca   = (const float*)d_in[1];
  const float* cb   = (const float*)d_in[2];
  const float* cc2  = (const float*)d_in[3];
  const float* cd   = (const float*)d_in[4];
  const int*   fidx = (const int*)d_in[5];
  const float* Wr   = (const float*)d_in[6];
  const float* br   = (const float*)d_in[7];
  const float* Wz   = (const float*)d_in[8];
  const float* bz   = (const float*)d_in[9];
  const float* Wxn  = (const float*)d_in[10];
  const float* bxn  = (const float*)d_in[11];
  const float* Whn  = (const float*)d_in[12];
  const float* bhn  = (const float*)d_in[13];
  const float* Wode = (const float*)d_in[14];
  const float* bode = (const float*)d_in[15];
  const float* Wlin = (const float*)d_in[16];
  const float* blin = (const float*)d_in[17];
  float* out = (float*)d_out;

  char* ws = (char*)d_ws;
  float4* si = (float4*)ws;                                     // TT*16 B
  int* anyobs = (int*)(ws + TT * 16);                           // TT*4 B
  unsigned char* obs = (unsigned char*)(ws + TT * 16 + TT * 4); // BB*TT B

  prep0<<<1, TT, 0, stream>>>(times, si, anyobs);
  prep_obs<<<(BB * TT) / 8, 256, 0, stream>>>(ca, cb, cc2, cd, si, anyobs, obs);
  ode_main<<<BB, 256, 0, stream>>>(ca, cb, cc2, cd, fidx, Wr, br, Wz, bz,
                                   Wxn, bxn, Whn, bhn, Wode, bode, Wlin, blin,
                                   si, anyobs, obs, out);
}

// Round 13
// 905.348 us; speedup vs baseline: 1.4712x; 1.0569x over previous
//
#include <hip/hip_runtime.h>
#include <string.h>

#define TT 512
#define BB 256
#define CC 65
#define HALFC 32
#define HID 128
#define ODIM 10

typedef _Float16 half2_t __attribute__((ext_vector_type(2)));
typedef _Float16 half8_t __attribute__((ext_vector_type(8)));

// tanh(x) = 2/(1+e^{-2x}) - 1
__device__ __forceinline__ float ftanh(float x) {
  float u = __builtin_amdgcn_exp2f(x * -2.885390082f);
  return fmaf(2.f, __builtin_amdgcn_rcpf(1.f + u), -1.f);
}
// sigmoid(x) = 1/(1+e^{-x})
__device__ __forceinline__ float fsig(float x) {
  float u = __builtin_amdgcn_exp2f(x * -1.442695041f);
  return __builtin_amdgcn_rcpf(1.f + u);
}

// pack two f32 -> half2 (v_cvt_pkrtz_f16_f32)
__device__ __forceinline__ half2_t h2cvt(float a, float b) {
  auto r = __builtin_amdgcn_cvt_pkrtz(a, b);
  half2_t o;
  memcpy(&o, &r, sizeof(o));
  return o;
}

__device__ __forceinline__ float fdot2h(half2_t a, half2_t b, float c) {
  return __builtin_amdgcn_fdot2(a, b, c, false);
}

template <int CTRL>
__device__ __forceinline__ float dpp_add(float x) {
  return x + __int_as_float(__builtin_amdgcn_update_dpp(
      0, __float_as_int(x), CTRL, 0xF, 0xF, true));
}
// 4-lane subgroup sum via row_shl: dest[i] = sum src[i..i+3]; valid (lane&3)==0.
__device__ __forceinline__ float red4(float x) {
  x = dpp_add<0x101>(x);  // row_shl:1
  x = dpp_add<0x102>(x);  // row_shl:2
  return x;
}

// Raw barrier: drain LDS ops, no vmcnt drain (global loads stay in flight).
__device__ __forceinline__ void block_sync_lds() {
  asm volatile("s_waitcnt lgkmcnt(0)" ::: "memory");
  __builtin_amdgcn_s_barrier();
  asm volatile("" ::: "memory");
}
__device__ __forceinline__ void vm_wait0() {
  asm volatile("s_waitcnt vmcnt(0)" ::: "memory");
}

// Per-t scalars: idx (int bits), fr, td, tsub
__global__ void prep0(const float* __restrict__ times, float4* __restrict__ si,
                      int* __restrict__ anyobs) {
  __shared__ float ts[TT];
  int t = threadIdx.x;
  ts[t] = times[t];
  __syncthreads();
  float tv = ts[t];
  int cnt = 0;
  for (int jj = 0; jj < TT; ++jj) cnt += (tv > ts[jj]) ? 1 : 0;
  int idx = cnt - 1;
  idx = min(max(idx, 0), TT - 2);
  float4 o;
  o.x = __int_as_float(idx);
  o.y = tv - ts[idx];
  o.z = (t == 0) ? 0.f : (tv - ts[t - 1]);
  o.w = (t == 0) ? ts[0] : ts[t - 1];
  si[t] = o;
  anyobs[t] = 0;
}

// obs[b,t] = max over diffed channels 1..32 > 0.5 ; anyobs[t] = OR over b
__global__ void prep_obs(const float* __restrict__ ca, const float* __restrict__ cb,
                         const float* __restrict__ cc2, const float* __restrict__ cd,
                         const float4* __restrict__ si, int* __restrict__ anyobs,
                         unsigned char* __restrict__ obs) {
  int grp = blockIdx.x * (blockDim.x >> 5) + (threadIdx.x >> 5);
  int lane = threadIdx.x & 31;
  int t = grp & (TT - 1);
  int b = grp / TT;
  int ch = 1 + lane;
  float4 s = si[t];
  int idx = __float_as_int(s.x);
  float fr = s.y;
  size_t base = ((size_t)b * (TT - 1) + idx) * CC + ch;
  float f3 = fr / 3.f;
  float v = ca[base] + (cb[base] + (0.5f * cc2[base] + cd[base] * f3) * fr) * fr;
  float D = v;
  if (t >= 1) {
    float4 sp = si[t - 1];
    int idxp = __float_as_int(sp.x);
    float frp = sp.y;
    size_t basep = ((size_t)b * (TT - 1) + idxp) * CC + ch;
    float f3p = frp / 3.f;
    float vp = ca[basep] + (cb[basep] + (0.5f * cc2[basep] + cd[basep] * f3p) * frp) * frp;
    D = v - vp;
  }
  float m = D;
  #pragma unroll
  for (int off = 16; off >= 1; off >>= 1) m = fmaxf(m, __shfl_xor(m, off));
  if (lane == 0) {
    unsigned char o = (m > 0.5f) ? (unsigned char)1 : (unsigned char)0;
    obs[(size_t)b * TT + t] = o;
    if (o) atomicOr(&anyobs[t], 1);
  }
}

// One block per batch element. 256 threads = 4 waves. Lane (p=lane>>2, kk=lane&3)
// owns output pair s = wv*16+p over k-slice [32kk, 32kk+32). f16 weights+state,
// v_dot2; x channel 0 in f32. Schedule: spline at loop top (prev-step prefetch),
// x-matvec partials in stage-2 shadow, GRU skipped when ob==0 (block-uniform).
__launch_bounds__(256, 1)
__global__ void ode_main(
    const float* __restrict__ ca, const float* __restrict__ cb,
    const float* __restrict__ cc2, const float* __restrict__ cd,
    const int* __restrict__ final_index,
    const float* __restrict__ Wr, const float* __restrict__ br,
    const float* __restrict__ Wz, const float* __restrict__ bz,
    const float* __restrict__ Wxn, const float* __restrict__ bxn,
    const float* __restrict__ Whn, const float* __restrict__ bhn,
    const float* __restrict__ Wode, const float* __restrict__ bode,
    const float* __restrict__ Wlin, const float* __restrict__ blin,
    const float4* __restrict__ si, const int* __restrict__ anyobs,
    const unsigned char* __restrict__ obsArr,
    float* __restrict__ out)
{
  __shared__ alignas(16) half2_t hS2[HID / 2];
  __shared__ alignas(16) half2_t vA2[HID / 2];
  __shared__ alignas(16) half2_t vB2[HID / 2];
  __shared__ alignas(16) _Float16 xh[HALFC];
  __shared__ float xs0f;
  __shared__ alignas(16) float4 siL[TT];
  __shared__ unsigned char flagL[TT];

  const int tid = threadIdx.x;
  const int b = blockIdx.x;
  const int lane = tid & 63;
  const int wv = tid >> 6;       // 0..3
  const int p = lane >> 2;       // 0..15
  const int kk = lane & 3;       // 0..3
  const int s = wv * 16 + p;     // output pair 0..63
  const int j0 = 2 * s;
  const int wbyte = 4 * s;       // write byte offset (half2)

  // ---- h-matvec weights f16 ----
  half2_t wodeH[32], whnH[32], wrhH[32], wzhH[32];
  #pragma unroll
  for (int i = 0; i < 16; ++i) {
    const int r0 = 32 * kk + 2 * i, r1 = r0 + 1;
    float2 q0, q1;
    q0 = *(const float2*)&Wode[r0 * HID + j0];
    q1 = *(const float2*)&Wode[r1 * HID + j0];
    wodeH[2*i] = h2cvt(q0.x, q1.x); wodeH[2*i+1] = h2cvt(q0.y, q1.y);
    q0 = *(const float2*)&Whn[r0 * HID + j0];
    q1 = *(const float2*)&Whn[r1 * HID + j0];
    whnH[2*i] = h2cvt(q0.x, q1.x); whnH[2*i+1] = h2cvt(q0.y, q1.y);
    q0 = *(const float2*)&Wr[(HALFC + r0) * HID + j0];
    q1 = *(const float2*)&Wr[(HALFC + r1) * HID + j0];
    wrhH[2*i] = h2cvt(q0.x, q1.x); wrhH[2*i+1] = h2cvt(q0.y, q1.y);
    q0 = *(const float2*)&Wz[(HALFC + r0) * HID + j0];
    q1 = *(const float2*)&Wz[(HALFC + r1) * HID + j0];
    wzhH[2*i] = h2cvt(q0.x, q1.x); wzhH[2*i+1] = h2cvt(q0.y, q1.y);
  }
  // x-part weights f16 over channels [8kk, 8kk+8)
  half2_t wrxH[8], wzxH[8], wxnH[8];
  #pragma unroll
  for (int i = 0; i < 4; ++i) {
    const int c0 = 8 * kk + 2 * i, c1 = c0 + 1;
    float2 q0, q1;
    q0 = *(const float2*)&Wr[c0 * HID + j0];
    q1 = *(const float2*)&Wr[c1 * HID + j0];
    wrxH[i] = h2cvt(q0.x, q1.x); wrxH[4+i] = h2cvt(q0.y, q1.y);
    q0 = *(const float2*)&Wz[c0 * HID + j0];
    q1 = *(const float2*)&Wz[c1 * HID + j0];
    wzxH[i] = h2cvt(q0.x, q1.x); wzxH[4+i] = h2cvt(q0.y, q1.y);
    q0 = *(const float2*)&Wxn[c0 * HID + j0];
    q1 = *(const float2*)&Wxn[c1 * HID + j0];
    wxnH[i] = h2cvt(q0.x, q1.x); wxnH[4+i] = h2cvt(q0.y, q1.y);
  }
  // channel 0 (dt channel, large): zero f16 weight, add in f32
  float wr0a = 0.f, wr0b = 0.f, wz0a = 0.f, wz0b = 0.f, wx0a = 0.f, wx0b = 0.f;
  if (kk == 0) {
    wrxH[0][0] = (_Float16)0.f; wrxH[4][0] = (_Float16)0.f;
    wzxH[0][0] = (_Float16)0.f; wzxH[4][0] = (_Float16)0.f;
    wxnH[0][0] = (_Float16)0.f; wxnH[4][0] = (_Float16)0.f;
    wr0a = Wr[j0];  wr0b = Wr[j0 + 1];
    wz0a = Wz[j0];  wz0b = Wz[j0 + 1];
    wx0a = Wxn[j0]; wx0b = Wxn[j0 + 1];
  }
  float bo0, bo1, bh0, bh1, br0, br1, bz0, bz1, bx0, bx1;
  { float2 q;
    q = *(const float2*)&bode[j0]; bo0 = q.x; bo1 = q.y;
    q = *(const float2*)&bhn [j0]; bh0 = q.x; bh1 = q.y;
    q = *(const float2*)&br  [j0]; br0 = q.x; br1 = q.y;
    q = *(const float2*)&bz  [j0]; bz0 = q.x; bz1 = q.y;
    q = *(const float2*)&bxn [j0]; bx0 = q.x; bx1 = q.y;
  }
  const int fidx = final_index[b];

  // ---- stage per-step metadata into LDS (one-time; 2 sweeps of 256) ----
  #pragma unroll
  for (int it = 0; it < 2; ++it) {
    const int tt = tid + it * 256;
    siL[tt] = si[tt];
    const int ao = anyobs[tt];
    const unsigned char o = obsArr[(size_t)b * TT + tt];
    flagL[tt] = (unsigned char)((ao ? 1 : 0) | (o ? 2 : 0));
  }
  if (tid < HID / 2) {
    const half2_t z2 = {(_Float16)0.f, (_Float16)0.f};
    hS2[tid] = z2; vA2[tid] = z2; vB2[tid] = z2;
  }
  if (tid < HALFC) xh[tid] = (_Float16)0.f;
  if (tid == 0) xs0f = 0.f;
  float hj0 = 0.f, hj1 = 0.f;  // fp32 master h, valid on kk==0 lanes
  float dtv = 0.f;             // valid on tid==0
  block_sync_lds();

  // matvec over linear f16 LDS vector: 4 b128 reads, 32 dot2, red4.
  auto mv = [&](const half2_t* __restrict__ buf, const half2_t (&w)[32],
                float& o0, float& o1) {
    half2_t v2[16];
    #pragma unroll
    for (int q = 0; q < 4; ++q) {
      const half8_t x8 = *(const half8_t*)((const char*)buf + 64 * kk + 16 * q);
      v2[4*q+0] = __builtin_shufflevector(x8, x8, 0, 1);
      v2[4*q+1] = __builtin_shufflevector(x8, x8, 2, 3);
      v2[4*q+2] = __builtin_shufflevector(x8, x8, 4, 5);
      v2[4*q+3] = __builtin_shufflevector(x8, x8, 6, 7);
    }
    float a0 = 0.f, a1 = 0.f, b0 = 0.f, b1 = 0.f;
    #pragma unroll
    for (int i = 0; i < 8; ++i) {
      a0 = fdot2h(v2[i],     w[2*i],       a0);
      a1 = fdot2h(v2[i],     w[2*i+1],     a1);
      b0 = fdot2h(v2[8 + i], w[2*(8+i)],   b0);
      b1 = fdot2h(v2[8 + i], w[2*(8+i)+1], b1);
    }
    o0 = red4(a0 + b0);
    o1 = red4(a1 + b1);
  };

  const int xch = wv * 8 + lane;   // valid when lane < 8
  const bool xlane = (lane < 8);

  float4 sv4 = siL[0];
  int flg = flagL[0];

  // issue x-coeff loads for t=0
  float xa = 0.f, xb = 0.f, xc = 0.f, xd = 0.f;
  float ya = 0.f, yb = 0.f, yc = 0.f, yd = 0.f;
  if (xlane) {
    const size_t base = ((size_t)b * (TT - 1) + __float_as_int(sv4.x)) * CC;
    const int ch = 33 + xch;
    xa = ca[base + ch]; xb = cb[base + ch]; xc = cc2[base + ch]; xd = cd[base + ch];
    if (tid == 0) { ya = ca[base]; yb = cb[base]; yc = cc2[base]; yd = cd[base]; }
  }

  for (int t = 0; ; ++t) {
    const float fr = sv4.y, td = sv4.z, tsub = sv4.w;
    const bool doGru = (flg & 2) != 0;   // block-uniform

    // ---- loop top: spline for step t (loads issued last iter) ----
    float xdelta = 0.f;
    vm_wait0();
    if (xlane) {
      const float f3 = fr * (1.f / 3.f);
      float sv = xa + (xb + (0.5f * xc + xd * f3) * fr) * fr;
      if (tid == 0) {
        const float s0 = ya + (yb + (0.5f * yc + yd * f3) * fr) * fr;
        xdelta = s0 - tsub;
        sv += dtv;       // Xp[:,0] += dt (dtv final from step t-1)
        xs0f = sv;
      }
      xh[xch] = (_Float16)sv;
    }

    // ---- prefetch next step's metadata + issue next x-coeff loads ----
    const int tn = (t < TT - 1) ? t + 1 : t;
    const float4 sv4N = siL[tn];
    const int flgN = flagL[tn];
    if (xlane) {
      const size_t base = ((size_t)b * (TT - 1) + __float_as_int(sv4N.x)) * CC;
      const int ch = 33 + xch;
      xa = ca[base + ch]; xb = cb[base + ch]; xc = cc2[base + ch]; xd = cd[base + ch];
      if (tid == 0) { ya = ca[base]; yb = cb[base]; yc = cc2[base]; yd = cd[base]; }
    }

    // x-matvec partials (computed in stage-2 shadow when t>0)
    float rxp0 = 0.f, rxp1 = 0.f, zxp0 = 0.f, zxp1 = 0.f, xxp0 = 0.f, xxp1 = 0.f;

    if (t > 0) {
      const float htd = 0.5f * td;
      float p0, p1, k0, k1, ks0, ks1;
      // stage 1: k1 = f(h)
      mv(hS2, wodeH, p0, p1);
      k0 = ftanh(p0 + bo0); k1 = ftanh(p1 + bo1);
      ks0 = k0; ks1 = k1;
      if (kk == 0)
        *(half2_t*)((char*)vA2 + wbyte) =
            h2cvt(fmaf(htd, k0, hj0), fmaf(htd, k1, hj1));
      block_sync_lds();   // publishes vA2 AND xh/xs0f
      // x-partials in stage-2's shadow
      if (doGru) {
        const half8_t x8 = *(const half8_t*)((const char*)xh + 16 * kk);
        half2_t xv2[4];
        xv2[0] = __builtin_shufflevector(x8, x8, 0, 1);
        xv2[1] = __builtin_shufflevector(x8, x8, 2, 3);
        xv2[2] = __builtin_shufflevector(x8, x8, 4, 5);
        xv2[3] = __builtin_shufflevector(x8, x8, 6, 7);
        #pragma unroll
        for (int i = 0; i < 4; ++i) {
          rxp0 = fdot2h(xv2[i], wrxH[i],   rxp0);
          rxp1 = fdot2h(xv2[i], wrxH[4+i], rxp1);
          zxp0 = fdot2h(xv2[i], wzxH[i],   zxp0);
          zxp1 = fdot2h(xv2[i], wzxH[4+i], zxp1);
          xxp0 = fdot2h(xv2[i], wxnH[i],   xxp0);
          xxp1 = fdot2h(xv2[i], wxnH[4+i], xxp1);
        }
        if (kk == 0) {
          const float x0 = xs0f;
          rxp0 = fmaf(x0, wr0a, rxp0); rxp1 = fmaf(x0, wr0b, rxp1);
          zxp0 = fmaf(x0, wz0a, zxp0); zxp1 = fmaf(x0, wz0b, zxp1);
          xxp0 = fmaf(x0, wx0a, xxp0); xxp1 = fmaf(x0, wx0b, xxp1);
        }
      }
      // stage 2: k2 = f(h + td/2 k1)
      mv(vA2, wodeH, p0, p1);
      k0 = ftanh(p0 + bo0); k1 = ftanh(p1 + bo1);
      ks0 = fmaf(2.f, k0, ks0); ks1 = fmaf(2.f, k1, ks1);
      if (kk == 0)
        *(half2_t*)((char*)vB2 + wbyte) =
            h2cvt(fmaf(htd, k0, hj0), fmaf(htd, k1, hj1));
      block_sync_lds();
      // stage 3: k3 = f(h + td/2 k2)
      mv(vB2, wodeH, p0, p1);
      k0 = ftanh(p0 + bo0); k1 = ftanh(p1 + bo1);
      ks0 = fmaf(2.f, k0, ks0); ks1 = fmaf(2.f, k1, ks1);
      if (kk == 0)
        *(half2_t*)((char*)vA2 + wbyte) =
            h2cvt(fmaf(td, k0, hj0), fmaf(td, k1, hj1));
      block_sync_lds();
      // stage 4: k4 = f(h + td k3); h += td/6 (k1+2k2+2k3+k4)
      mv(vA2, wodeH, p0, p1);
      k0 = ftanh(p0 + bo0); k1 = ftanh(p1 + bo1);
      ks0 += k0; ks1 += k1;
      hj0 = fmaf(td * (1.f / 6.f), ks0, hj0);
      hj1 = fmaf(td * (1.f / 6.f), ks1, hj1);
      if (kk == 0)
        *(half2_t*)((char*)vB2 + wbyte) = h2cvt(hj0, hj1);
      block_sync_lds();   // publishes vB2 (h_evolved)
    } else {
      block_sync_lds();   // t==0: publish xh/xs0f (vB2 already zeros)
      if (doGru) {
        const half8_t x8 = *(const half8_t*)((const char*)xh + 16 * kk);
        half2_t xv2[4];
        xv2[0] = __builtin_shufflevector(x8, x8, 0, 1);
        xv2[1] = __builtin_shufflevector(x8, x8, 2, 3);
        xv2[2] = __builtin_shufflevector(x8, x8, 4, 5);
        xv2[3] = __builtin_shufflevector(x8, x8, 6, 7);
        #pragma unroll
        for (int i = 0; i < 4; ++i) {
          rxp0 = fdot2h(xv2[i], wrxH[i],   rxp0);
          rxp1 = fdot2h(xv2[i], wrxH[4+i], rxp1);
          zxp0 = fdot2h(xv2[i], wzxH[i],   zxp0);
          zxp1 = fdot2h(xv2[i], wzxH[4+i], zxp1);
          xxp0 = fdot2h(xv2[i], wxnH[i],   xxp0);
          xxp1 = fdot2h(xv2[i], wxnH[4+i], xxp1);
        }
        if (kk == 0) {
          const float x0 = xs0f;
          rxp0 = fmaf(x0, wr0a, rxp0); rxp1 = fmaf(x0, wr0b, rxp1);
          zxp0 = fmaf(x0, wz0a, zxp0); zxp1 = fmaf(x0, wz0b, zxp1);
          xxp0 = fmaf(x0, wx0a, xxp0); xxp1 = fmaf(x0, wx0b, xxp1);
        }
      }
    }

    // ---- GRU (skipped entirely when this batch has no observation) ----
    if (doGru) {
      half2_t v2[16];
      #pragma unroll
      for (int q = 0; q < 4; ++q) {
        const half8_t x8 = *(const half8_t*)((const char*)vB2 + 64 * kk + 16 * q);
        v2[4*q+0] = __builtin_shufflevector(x8, x8, 0, 1);
        v2[4*q+1] = __builtin_shufflevector(x8, x8, 2, 3);
        v2[4*q+2] = __builtin_shufflevector(x8, x8, 4, 5);
        v2[4*q+3] = __builtin_shufflevector(x8, x8, 6, 7);
      }
      float rp0 = rxp0, rp1 = rxp1, zp0 = zxp0, zp1 = zxp1;
      float gp0 = 0.f, gp1 = 0.f, xp0 = xxp0, xp1 = xxp1;
      #pragma unroll
      for (int i = 0; i < 16; ++i) {
        rp0 = fdot2h(v2[i], wrhH[2*i],   rp0);
        rp1 = fdot2h(v2[i], wrhH[2*i+1], rp1);
        zp0 = fdot2h(v2[i], wzhH[2*i],   zp0);
        zp1 = fdot2h(v2[i], wzhH[2*i+1], zp1);
        gp0 = fdot2h(v2[i], whnH[2*i],   gp0);
        gp1 = fdot2h(v2[i], whnH[2*i+1], gp1);
      }
      rp0 = red4(rp0); rp1 = red4(rp1);
      zp0 = red4(zp0); zp1 = red4(zp1);
      gp0 = red4(gp0); gp1 = red4(gp1);
      xp0 = red4(xp0); xp1 = red4(xp1);
      const float r0 = fsig(rp0 + br0), r1 = fsig(rp1 + br1);
      const float z0 = fsig(zp0 + bz0), z1 = fsig(zp1 + bz1);
      const float n0 = ftanh(xp0 + bx0 + (gp0 + bh0) * r0);
      const float n1 = ftanh(xp1 + bx1 + (gp1 + bh1) * r1);
      hj0 = fmaf(z0, hj0 - n0, n0);   // apply == doGru (aob implied by ob)
      hj1 = fmaf(z1, hj1 - n1, n1);
      if (kk == 0)
        *(half2_t*)((char*)hS2 + wbyte) = h2cvt(hj0, hj1);
    } else {
      if (tid == 0 && (flg & 1)) dtv += xdelta;   // dt += Xi[:,0] (no obs here)
    }

    if (t == fidx) break;
    sv4 = sv4N;
    flg = flgN;
    if (doGru) block_sync_lds();   // publish hS2 before next stage 1
  }

  block_sync_lds();
  // final projection: out = h @ W_lin + b_lin (hS2 is LINEAR)
  if (tid < ODIM) {
    float acc = blin[tid];
    const _Float16* hf = (const _Float16*)hS2;
    #pragma unroll 8
    for (int q = 0; q < HID; ++q) {
      const float hv = (float)hf[q];
      acc = fmaf(hv, Wlin[q * ODIM + tid], acc);
    }
    out[b * ODIM + tid] = acc;
  }
}

extern "C" void kernel_launch(void* const* d_in, const int* in_sizes, int n_in,
                              void* d_out, int out_size, void* d_ws, size_t ws_size,
                              hipStream_t stream) {
  const float* times = (const float*)d_in[0];
  const float* ca   = (const float*)d_in[1];
  const float* cb   = (const float*)d_in[2];
  const float* cc2  = (const float*)d_in[3];
  const float* cd   = (const float*)d_in[4];
  const int*   fidx = (const int*)d_in[5];
  const float* Wr   = (const float*)d_in[6];
  const float* br   = (const float*)d_in[7];
  const float* Wz   = (const float*)d_in[8];
  const float* bz   = (const float*)d_in[9];
  const float* Wxn  = (const float*)d_in[10];
  const float* bxn  = (const float*)d_in[11];
  const float* Whn  = (const float*)d_in[12];
  const float* bhn  = (const float*)d_in[13];
  const float* Wode = (const float*)d_in[14];
  const float* bode = (const float*)d_in[15];
  const float* Wlin = (const float*)d_in[16];
  const float* blin = (const float*)d_in[17];
  float* out = (float*)d_out;

  char* ws = (char*)d_ws;
  float4* si = (float4*)ws;                                     // TT*16 B
  int* anyobs = (int*)(ws + TT * 16);                           // TT*4 B
  unsigned char* obs = (unsigned char*)(ws + TT * 16 + TT * 4); // BB*TT B

  prep0<<<1, TT, 0, stream>>>(times, si, anyobs);
  prep_obs<<<(BB * TT) / 8, 256, 0, stream>>>(ca, cb, cc2, cd, si, anyobs, obs);
  ode_main<<<BB, 256, 0, stream>>>(ca, cb, cc2, cd, fidx, Wr, br, Wz, bz,
                                   Wxn, bxn, Whn, bhn, Wode, bode, Wlin, blin,
                                   si, anyobs, obs, out);
}